// Round 11
// baseline (78.946 us; speedup 1.0000x reference)
//
#include <hip/hip_runtime.h>

// TemporalVoxelAttention — MFMA (bf16) fused.
// R11: CODE-SIZE probe. R9/R10 evidence: throughput = 0.34 groups/us/CU fused
// vs 0.49 for the no-agg kernel — scales with dynamic instruction count, is
// invariant to waves/ILP/LDS geometry, and all pipes are <40% busy. Candidate
// bound: instruction fetch (fully-unrolled ~28KB straight-line stream, ~9
// waves at distinct offsets). Probe: roll the nt-loops (unroll 1) where the
// body has no register-array-by-nt (rule #20), hoist G's gate shuffles, and
// shrink f2bf 4ops->2ops (round-half-up; absmax headroom 3x). ~45% smaller
// code, ~12% fewer dynamic instrs, geometry identical to R10 (2 waves x 64,
// 16KB LDS, fence-free). Asymmetric read: win->fetch-bound confirmed;
// loss->latency-bound confirmed (rolled loops expose per-iter ldB latency).

using bf16x8 = __attribute__((ext_vector_type(8))) __bf16;
using f32x4  = __attribute__((ext_vector_type(4))) float;

#define DEV static __device__ __forceinline__

DEV unsigned short f2bf(float f){
  union { float f; unsigned int i; } v; v.f = f;
  return (unsigned short)((v.i + 0x8000u) >> 16);   // round-half-up to bf16
}

// LDS matrices: [rows][64] bf16 (128-B rows), XOR-swizzle byte ^= ((row&7)<<4).
DEV unsigned short* lp(unsigned short* base, int row, int col){
  int byte = (col << 1) ^ ((row & 7) << 4);
  return (unsigned short*)((char*)base + (row << 7) + byte);
}

// A-fragment: lane holds A[row = mt*16 + (lane&15)][k = kt*32 + (lane>>4)*8 + i]
DEV bf16x8 ldA(const unsigned short* base, int mt, int kt, int lane){
  int row = mt*16 + (lane & 15);
  int col = kt*32 + ((lane >> 4) << 3);
  return *(const bf16x8*)lp((unsigned short*)base, row, col);
}
// B-fragment: pre-packed in ws, lane-contiguous 16B
DEV bf16x8 ldB(const unsigned short* w, int frag, int lane){
  return *(const bf16x8*)(w + (size_t)frag*512 + (size_t)lane*8);
}
// C/D: col = lane&15, row = mt*16 + (lane>>4)*4 + r
DEV void stC(unsigned short* base, int mt, int nt, f32x4 c, int lane){
  int col  = nt*16 + (lane & 15);
  int row0 = mt*16 + ((lane >> 4) << 2);
  #pragma unroll
  for (int r = 0; r < 4; ++r) *lp(base, row0 + r, col) = f2bf(c[r]);
}
DEV f32x4 MF(bf16x8 a, bf16x8 b, f32x4 c){
  return __builtin_amdgcn_mfma_f32_16x16x32_bf16(a, b, c, 0, 0, 0);
}

DEV void ld16(const unsigned short* base, int row, int col0, float* o){
  uint4 a = *(const uint4*)lp((unsigned short*)base, row, col0);
  uint4 b = *(const uint4*)lp((unsigned short*)base, row, col0 + 8);
  unsigned int w[8] = {a.x, a.y, a.z, a.w, b.x, b.y, b.z, b.w};
  #pragma unroll
  for (int i = 0; i < 8; ++i){
    union { unsigned int u; float f; } lo, hi;
    lo.u = w[i] << 16; hi.u = w[i] & 0xFFFF0000u;
    o[2*i] = lo.f; o[2*i+1] = hi.f;
  }
}
DEV void st16(unsigned short* base, int row, int col0, const float* f){
  unsigned int w[8];
  #pragma unroll
  for (int i = 0; i < 8; ++i)
    w[i] = (unsigned int)f2bf(f[2*i]) | ((unsigned int)f2bf(f[2*i+1]) << 16);
  *(uint4*)lp(base, row, col0)     = make_uint4(w[0], w[1], w[2], w[3]);
  *(uint4*)lp(base, row, col0 + 8) = make_uint4(w[4], w[5], w[6], w[7]);
}

DEV bf16x8 pack8(const float* f){
  union { bf16x8 v; unsigned short u[8]; } r;
  #pragma unroll
  for (int i = 0; i < 8; ++i) r.u[i] = f2bf(f[i]);
  return r.v;
}

// LayerNorm over 64 cols for one 16-row M-tile held as 4 C-frags.
DEV void layer_norm16(f32x4 x[4], const float* g, const float* b, int lane){
  float s[4], s2[4];
  #pragma unroll
  for (int r = 0; r < 4; ++r){
    s[r]  = x[0][r] + x[1][r] + x[2][r] + x[3][r];
    s2[r] = x[0][r]*x[0][r] + x[1][r]*x[1][r] + x[2][r]*x[2][r] + x[3][r]*x[3][r];
  }
  #pragma unroll
  for (int o = 1; o <= 8; o <<= 1){
    #pragma unroll
    for (int r = 0; r < 4; ++r){
      s[r]  += __shfl_xor(s[r],  o);
      s2[r] += __shfl_xor(s2[r], o);
    }
  }
  float mu[4], rs[4];
  #pragma unroll
  for (int r = 0; r < 4; ++r){
    mu[r] = s[r] * (1.f/64.f);
    float var = s2[r] * (1.f/64.f) - mu[r]*mu[r];
    rs[r] = rsqrtf(var + 1e-5f);
  }
  const int cl = lane & 15;
  #pragma unroll
  for (int nt = 0; nt < 4; ++nt){
    float gg = g[nt*16 + cl], bb = b[nt*16 + cl];
    #pragma unroll
    for (int r = 0; r < 4; ++r)
      x[nt][r] = (x[nt][r] - mu[r]) * rs[r] * gg + bb;
  }
}

// ---------------- weight packing (unchanged) ----------------
// 0: pp_w1 (K=8 pad 32, N=64)   base 0,  4 frags
// 1: pp_w2 (K=64,  N=64)        base 4,  8
// 2: in_proj (K=64, N=192)      base 12, 24
// 3: out_w (K=64, N=64)         base 36, 8
// 4: ffn_w1 (K=64, N=128)       base 44, 16
// 5: ffn_w2 (K=128, N=64)       base 60, 16
// 6: op_w1 (K=64, N=64)         base 76, 8
// 7: op_w2 (K=64, N=64)         base 84, 8   -> 92 frags total
__global__ void tva_pack_weights(const float* __restrict__ pp_w1, const float* __restrict__ pp_w2,
                                 const float* __restrict__ in_proj_w, const float* __restrict__ out_w,
                                 const float* __restrict__ ffn_w1, const float* __restrict__ ffn_w2,
                                 const float* __restrict__ op_w1, const float* __restrict__ op_w2,
                                 unsigned short* __restrict__ ws)
{
  int b = blockIdx.x, lane = threadIdx.x;
  const float* W; int base, ktiles, K;
  if      (b < 4)  { W = pp_w1;     base = 0;  ktiles = 1; K = 8;   }
  else if (b < 12) { W = pp_w2;     base = 4;  ktiles = 2; K = 64;  }
  else if (b < 36) { W = in_proj_w; base = 12; ktiles = 2; K = 64;  }
  else if (b < 44) { W = out_w;     base = 36; ktiles = 2; K = 64;  }
  else if (b < 60) { W = ffn_w1;    base = 44; ktiles = 2; K = 64;  }
  else if (b < 76) { W = ffn_w2;    base = 60; ktiles = 4; K = 128; }
  else if (b < 84) { W = op_w1;     base = 76; ktiles = 2; K = 64;  }
  else             { W = op_w2;     base = 84; ktiles = 2; K = 64;  }
  int local = b - base;
  int nt = local / ktiles, kt = local % ktiles;
  int n  = nt*16 + (lane & 15);
  int k0 = kt*32 + ((lane >> 4) << 3);
  unsigned short* dst = ws + (size_t)b*512 + (size_t)lane*8;
  #pragma unroll
  for (int i = 0; i < 8; ++i){
    int k = k0 + i;
    float v = (k < K) ? W[(size_t)n*K + k] : 0.0f;
    dst[i] = f2bf(v);
  }
}

// ---------------- main kernel ----------------
__global__ __launch_bounds__(128)
void tva_main(const float* __restrict__ vf, const float* __restrict__ vox,
              const int* __restrict__ num_points,
              const float* __restrict__ pp_b1, const float* __restrict__ pp_b2,
              const float* __restrict__ ipb,  const float* __restrict__ outb,
              const float* __restrict__ ln1g, const float* __restrict__ ln1b,
              const float* __restrict__ f1b,  const float* __restrict__ f2bv,
              const float* __restrict__ ln2g, const float* __restrict__ ln2b,
              const float* __restrict__ o1b,  const float* __restrict__ o2b,
              const unsigned short* __restrict__ wfrag,
              float* __restrict__ out, int nvox)
{
  __shared__ unsigned short smem[2 * 64 * 64];   // 16 KB: 2 waves x 8 KB
  const int tid  = threadIdx.x;
  const int wv   = tid >> 6;
  const int lane = tid & 63;
  unsigned short* X = smem + wv * (64*64);  // rows 0..47: hidden -> tok12 -> K -> V -> ffn-h -> op1-h
  unsigned short* Q = X + 48*64;            // rows 0..15: q -> ctx -> postLN1 -> postLN2

  const int v0 = (blockIdx.x * 2 + wv) * 16;
  if (v0 >= nvox) return;                   // tail waves (no barriers -> safe)
  const int cl = lane & 15;
  const int r0 = (lane >> 4) << 2;

  // ======== Phase A: point aggregation (4 lanes per voxel) ========
  const int vi = lane >> 2, pq = lane & 3;
  const int np = num_points[v0 + vi];
  float cs[8] = {0,0,0,0,0,0,0,0}, hs[8] = {0,0,0,0,0,0,0,0};
  float cc = 0.f, hc = 0.f;
  const float4* vp = (const float4*)(vox + (size_t)(v0 + vi) * 384);
  #pragma unroll
  for (int k = 0; k < 12; ++k){
    int p = pq + (k << 2);
    float4 a = vp[p*2], b = vp[p*2 + 1];
    float pm = (p < np) ? 1.f : 0.f;
    float cm = (b.w > 0.5f) ? pm : 0.f;   // current: flag>0.5 & in-range
    float hm = pm - cm;                   // history: in-range & !current
    cc += cm; hc += hm;
    cs[0] += a.x*cm; cs[1] += a.y*cm; cs[2] += a.z*cm; cs[3] += a.w*cm;
    cs[4] += b.x*cm; cs[5] += b.y*cm; cs[6] += b.z*cm; cs[7] += b.w*cm;
    hs[0] += a.x*hm; hs[1] += a.y*hm; hs[2] += a.z*hm; hs[3] += a.w*hm;
    hs[4] += b.x*hm; hs[5] += b.y*hm; hs[6] += b.z*hm; hs[7] += b.w*hm;
  }
  #pragma unroll
  for (int o = 1; o <= 2; o <<= 1){
    cc += __shfl_xor(cc, o); hc += __shfl_xor(hc, o);
    #pragma unroll
    for (int j = 0; j < 8; ++j){
      cs[j] += __shfl_xor(cs[j], o);
      hs[j] += __shfl_xor(hs[j], o);
    }
  }
  const float icc = 1.f / fmaxf(cc, 1.f);
  const float ihc = 1.f / fmaxf(hc, 1.f);
  const unsigned int myfw = (cc > 0.f ? 1u : 0u) | (hc > 0.f ? 2u : 0u);

  // Build pp-GEMM1 A-fragments in-register (16 shuffles; no LDS staging).
  bf16x8 ac, ah;
  {
    const int src = cl * 4;   // any lane of voxel (lane&15) has the full sums
    float cf[8], hf[8];
    #pragma unroll
    for (int i = 0; i < 8; ++i){
      cf[i] = __shfl(cs[i]*icc, src);
      hf[i] = __shfl(hs[i]*ihc, src);
    }
    union { bf16x8 v; unsigned short u[8]; } rc, rh;
    #pragma unroll
    for (int i = 0; i < 8; ++i){
      rc.u[i] = (lane < 16) ? f2bf(cf[i]) : (unsigned short)0;
      rh.u[i] = (lane < 16) ? f2bf(hf[i]) : (unsigned short)0;
    }
    ac = rc.v; ah = rh.v;
  }

  // ======== Phase B: point_proj (8->64 relu, 64->64) ========
  #pragma unroll 1
  for (int nt = 0; nt < 4; ++nt){
    float bb = pp_b1[nt*16 + cl];
    f32x4 c0 = {bb, bb, bb, bb}, c1 = {bb, bb, bb, bb};
    bf16x8 B = ldB(wfrag, nt, lane);
    c0 = MF(ac, B, c0);
    c1 = MF(ah, B, c1);
    #pragma unroll
    for (int r = 0; r < 4; ++r){ c0[r] = fmaxf(c0[r], 0.f); c1[r] = fmaxf(c1[r], 0.f); }
    stC(X, 0, nt, c0, lane);   // hidden(cur) rows 0..15
    stC(X, 1, nt, c1, lane);   // hidden(his) rows 16..31
  }
  {
    bf16x8 hfr[2][2];
    #pragma unroll
    for (int m = 0; m < 2; ++m)
      #pragma unroll
      for (int kt = 0; kt < 2; ++kt) hfr[m][kt] = ldA(X, m, kt, lane);
    // loads precede the overwriting stores in program order (per-wave order)
    #pragma unroll 1
    for (int nt = 0; nt < 4; ++nt){
      float bb = pp_b2[nt*16 + cl];
      bf16x8 W0 = ldB(wfrag, 4 + nt*2 + 0, lane);
      bf16x8 W1 = ldB(wfrag, 4 + nt*2 + 1, lane);
      #pragma unroll
      for (int m = 0; m < 2; ++m){
        f32x4 c = {bb, bb, bb, bb};
        c = MF(hfr[m][0], W0, c);
        c = MF(hfr[m][1], W1, c);
        stC(X, m, nt, c, lane);   // token1 rows 0..15, token2 rows 16..31
      }
    }
  }

  // ======== Phase C: QKV projections ========
  bf16x8 at[3][2];
  {
    // token0 A-frags straight from global vf (f32 -> bf16)
    const float* s = vf + (size_t)(v0 + cl) * 64 + ((lane >> 4) << 3);
    #pragma unroll
    for (int kt = 0; kt < 2; ++kt){
      float4 x0 = *(const float4*)(s + kt*32);
      float4 x1 = *(const float4*)(s + kt*32 + 4);
      float f[8] = {x0.x, x0.y, x0.z, x0.w, x1.x, x1.y, x1.z, x1.w};
      at[0][kt] = pack8(f);
    }
    #pragma unroll
    for (int kt = 0; kt < 2; ++kt){
      at[1][kt] = ldA(X, 0, kt, lane);
      at[2][kt] = ldA(X, 1, kt, lane);
    }
  }
  // q (token0 rows only), pre-scaled by 1/sqrt(DH)=0.25 -> Q
  #pragma unroll 1
  for (int nt = 0; nt < 4; ++nt){
    float bb = ipb[nt*16 + cl];
    f32x4 c = {bb, bb, bb, bb};
    c = MF(at[0][0], ldB(wfrag, 12 + nt*2 + 0, lane), c);
    c = MF(at[0][1], ldB(wfrag, 12 + nt*2 + 1, lane), c);
    #pragma unroll
    for (int r = 0; r < 4; ++r) c[r] *= 0.25f;
    stC(Q, 0, nt, c, lane);
  }
  // K (3 tokens) -> X rows 0..47 (token1/2 A-frags already in regs)
  #pragma unroll 1
  for (int nt = 0; nt < 4; ++nt){
    int ntg = 4 + nt;
    float bb = ipb[64 + nt*16 + cl];
    bf16x8 W0 = ldB(wfrag, 12 + ntg*2 + 0, lane);
    bf16x8 W1 = ldB(wfrag, 12 + ntg*2 + 1, lane);
    #pragma unroll
    for (int m = 0; m < 3; ++m){
      f32x4 c = {bb, bb, bb, bb};
      c = MF(at[m][0], W0, c);
      c = MF(at[m][1], W1, c);
      stC(X, m, nt, c, lane);
    }
  }

  // ======== Phase D1: scores + softmax (lane = (voxel, head)) ========
  const int av = cl, hh2 = lane >> 4;
  float p0, p1, p2;
  {
    unsigned int fw = (unsigned int)__shfl((int)myfw, av*4);
    bool caZ = (fw & 1u) != 0, hpZ = (fw & 2u) != 0;
    float q[16]; ld16(Q, av, hh2*16, q);
    float sc[3];
    #pragma unroll
    for (int m = 0; m < 3; ++m){
      float kv[16]; ld16(X, m*16 + av, hh2*16, kv);
      float d = 0.f;
      #pragma unroll
      for (int j = 0; j < 16; ++j) d += q[j]*kv[j];
      sc[m] = d;
    }
    float mx = sc[0];
    mx = caZ ? fmaxf(mx, sc[1]) : mx;
    mx = hpZ ? fmaxf(mx, sc[2]) : mx;
    p0 = __expf(sc[0] - mx);
    p1 = caZ ? __expf(sc[1] - mx) : 0.f;
    p2 = hpZ ? __expf(sc[2] - mx) : 0.f;
    float inv = 1.f / (p0 + p1 + p2);
    p0 *= inv; p1 *= inv; p2 *= inv;
  }

  // ======== Phase C2: V projection -> X (K reads precede in program order) ====
  #pragma unroll 1
  for (int nt = 0; nt < 4; ++nt){
    int ntg = 8 + nt;
    float bb = ipb[128 + nt*16 + cl];
    bf16x8 W0 = ldB(wfrag, 12 + ntg*2 + 0, lane);
    bf16x8 W1 = ldB(wfrag, 12 + ntg*2 + 1, lane);
    #pragma unroll
    for (int m = 0; m < 3; ++m){
      f32x4 c = {bb, bb, bb, bb};
      c = MF(at[m][0], W0, c);
      c = MF(at[m][1], W1, c);
      stC(X, m, nt, c, lane);
    }
  }

  // ======== Phase D2: ctx = p . V  -> Q (overwrites q) ========
  {
    float ctx[16];
    float vv[16];
    ld16(X, av, hh2*16, vv);
    #pragma unroll
    for (int j = 0; j < 16; ++j) ctx[j] = p0*vv[j];
    ld16(X, 16 + av, hh2*16, vv);
    #pragma unroll
    for (int j = 0; j < 16; ++j) ctx[j] += p1*vv[j];
    ld16(X, 32 + av, hh2*16, vv);
    #pragma unroll
    for (int j = 0; j < 16; ++j) ctx[j] += p2*vv[j];
    st16(Q, av, hh2*16, ctx);
  }

  // ======== Phase E: attn_out + residual + LN1 (token0 only) — unrolled ====
  f32x4 res1[4];
  {
    bf16x8 a0 = ldA(Q, 0, 0, lane), a1 = ldA(Q, 0, 1, lane);
    float rv[16];
    #pragma unroll
    for (int nt = 0; nt < 4; ++nt)
      #pragma unroll
      for (int r = 0; r < 4; ++r)
        rv[nt*4 + r] = vf[(size_t)(v0 + r0 + r)*64 + nt*16 + cl];
    #pragma unroll
    for (int nt = 0; nt < 4; ++nt){
      float bb = outb[nt*16 + cl];
      f32x4 c = {bb, bb, bb, bb};
      c = MF(a0, ldB(wfrag, 36 + nt*2 + 0, lane), c);
      c = MF(a1, ldB(wfrag, 36 + nt*2 + 1, lane), c);
      #pragma unroll
      for (int r = 0; r < 4; ++r) c[r] += rv[nt*4 + r];
      res1[nt] = c;
    }
    layer_norm16(res1, ln1g, ln1b, lane);
    #pragma unroll
    for (int nt = 0; nt < 4; ++nt) stC(Q, 0, nt, res1[nt], lane);
  }

  // ======== Phase F: FFN (64->128 relu ->64) + residual + LN2 ========
  f32x4 tk2[4];
  {
    bf16x8 a0 = ldA(Q, 0, 0, lane), a1 = ldA(Q, 0, 1, lane);
    #pragma unroll
    for (int nt = 0; nt < 4; ++nt){
      float bb = f2bv[nt*16 + cl];
      tk2[nt] = (f32x4){bb, bb, bb, bb};
    }
    // h cols 0..63 (rolled)
    #pragma unroll 1
    for (int nt = 0; nt < 4; ++nt){
      float bb = f1b[nt*16 + cl];
      f32x4 c = {bb, bb, bb, bb};
      c = MF(a0, ldB(wfrag, 44 + nt*2 + 0, lane), c);
      c = MF(a1, ldB(wfrag, 44 + nt*2 + 1, lane), c);
      #pragma unroll
      for (int r = 0; r < 4; ++r) c[r] = fmaxf(c[r], 0.f);
      stC(X, 0, nt, c, lane);
    }
    {
      bf16x8 h0 = ldA(X, 0, 0, lane), h1 = ldA(X, 0, 1, lane);
      #pragma unroll
      for (int nt = 0; nt < 4; ++nt){
        tk2[nt] = MF(h0, ldB(wfrag, 60 + nt*4 + 0, lane), tk2[nt]);
        tk2[nt] = MF(h1, ldB(wfrag, 60 + nt*4 + 1, lane), tk2[nt]);
      }
    }
    // h cols 64..127 (h0/h1 loads precede these stores in program order)
    #pragma unroll 1
    for (int nt = 4; nt < 8; ++nt){
      float bb = f1b[nt*16 + cl];
      f32x4 c = {bb, bb, bb, bb};
      c = MF(a0, ldB(wfrag, 44 + nt*2 + 0, lane), c);
      c = MF(a1, ldB(wfrag, 44 + nt*2 + 1, lane), c);
      #pragma unroll
      for (int r = 0; r < 4; ++r) c[r] = fmaxf(c[r], 0.f);
      stC(X, 0, nt - 4, c, lane);
    }
    {
      bf16x8 h0 = ldA(X, 0, 0, lane), h1 = ldA(X, 0, 1, lane);
      #pragma unroll
      for (int nt = 0; nt < 4; ++nt){
        tk2[nt] = MF(h0, ldB(wfrag, 60 + nt*4 + 2, lane), tk2[nt]);
        tk2[nt] = MF(h1, ldB(wfrag, 60 + nt*4 + 3, lane), tk2[nt]);
      }
    }
    #pragma unroll
    for (int nt = 0; nt < 4; ++nt)
      #pragma unroll
      for (int r = 0; r < 4; ++r) tk2[nt][r] += res1[nt][r];
    layer_norm16(tk2, ln2g, ln2b, lane);
    #pragma unroll
    for (int nt = 0; nt < 4; ++nt) stC(Q, 0, nt, tk2[nt], lane);
  }

  // ======== Phase G: output MLP + gate + final residual ========
  {
    bf16x8 a0 = ldA(Q, 0, 0, lane), a1 = ldA(Q, 0, 1, lane);
    #pragma unroll 1
    for (int nt = 0; nt < 4; ++nt){
      float bb = o1b[nt*16 + cl];
      f32x4 c = {bb, bb, bb, bb};
      c = MF(a0, ldB(wfrag, 76 + nt*2 + 0, lane), c);
      c = MF(a1, ldB(wfrag, 76 + nt*2 + 1, lane), c);
      #pragma unroll
      for (int r = 0; r < 4; ++r) c[r] = fmaxf(c[r], 0.f);
      stC(X, 0, nt, c, lane);
    }
    bf16x8 b0 = ldA(X, 0, 0, lane), b1 = ldA(X, 0, 1, lane);
    // hoist the per-row history gates out of the nt-loop (they repeat)
    float keep[4];
    #pragma unroll
    for (int r = 0; r < 4; ++r){
      unsigned int fw2 = (unsigned int)__shfl((int)myfw, (r0 + r)*4);
      keep[r] = (fw2 & 2u) ? 1.f : 0.f;
    }
    #pragma unroll 1
    for (int nt = 0; nt < 4; ++nt){
      float bb = o2b[nt*16 + cl];
      f32x4 c = {bb, bb, bb, bb};
      c = MF(b0, ldB(wfrag, 84 + nt*2 + 0, lane), c);
      c = MF(b1, ldB(wfrag, 84 + nt*2 + 1, lane), c);
      #pragma unroll
      for (int r = 0; r < 4; ++r){
        size_t idx = (size_t)(v0 + r0 + r)*64 + nt*16 + cl;
        out[idx] = vf[idx] + keep[r] * c[r];
      }
    }
  }
}

extern "C" void kernel_launch(void* const* d_in, const int* in_sizes, int n_in,
                              void* d_out, int out_size, void* d_ws, size_t ws_size,
                              hipStream_t stream)
{
  (void)n_in; (void)out_size; (void)ws_size;
  const float* vf    = (const float*)d_in[0];
  const float* vox   = (const float*)d_in[1];
  const float* pp_w1 = (const float*)d_in[2];
  const float* pp_b1 = (const float*)d_in[3];
  const float* pp_w2 = (const float*)d_in[4];
  const float* pp_b2 = (const float*)d_in[5];
  const float* ipw   = (const float*)d_in[6];
  const float* ipb   = (const float*)d_in[7];
  const float* outw  = (const float*)d_in[8];
  const float* outb  = (const float*)d_in[9];
  const float* ln1g  = (const float*)d_in[10];
  const float* ln1b  = (const float*)d_in[11];
  const float* f1w   = (const float*)d_in[12];
  const float* f1b   = (const float*)d_in[13];
  const float* f2w   = (const float*)d_in[14];
  const float* f2b   = (const float*)d_in[15];
  const float* ln2g  = (const float*)d_in[16];
  const float* ln2b  = (const float*)d_in[17];
  const float* o1w   = (const float*)d_in[18];
  const float* o1b   = (const float*)d_in[19];
  const float* o2w   = (const float*)d_in[20];
  const float* o2b   = (const float*)d_in[21];
  const int*   npts  = (const int*)d_in[22];
  unsigned short* wfrag = (unsigned short*)d_ws;   // 92*512*2 = 94208 B
  float* out = (float*)d_out;

  const int nvox = in_sizes[0] / 64;       // 100000
  const int ngrp = nvox / 16;              // 6250 wave-groups
  const int nblk = (ngrp + 1) / 2;         // 3125 blocks x 2 waves
  tva_pack_weights<<<92, 64, 0, stream>>>(pp_w1, pp_w2, ipw, outw, f1w, f2w, o1w, o2w, wfrag);
  tva_main<<<nblk, 128, 0, stream>>>(vf, vox, npts, pp_b1, pp_b2, ipb, outb,
                                     ln1g, ln1b, f1b, f2b, ln2g, ln2b, o1b, o2b,
                                     wfrag, out, nvox);
}

// Round 12
// 71.663 us; speedup vs baseline: 1.1016x; 1.1016x over previous
//
#include <hip/hip_runtime.h>

// TemporalVoxelAttention — MFMA (bf16) fused.
// R12: REGISTER-RESIDENT WEIGHT PREFETCH. R11's rolled-loop regression
// confirmed latency-bound with ldB (weight-frag L2 loads, ~60/wave) as the
// dominant serialized term: VGPR=84 means the compiler keeps only ~2-4 frags
// in flight, so loads proceed in tiny batches of ~200-600cyc each. Measured
// residency (9.2 waves/CU) is BELOW the 16-wave VGPR cap -> spending up to
// 128 VGPR is free. Fix: two 8-frag register batches WA/WB (32 VGPR each),
// loaded in strict alternation one GEMM-phase ahead; all indices static.
// Geometry = R10 (2 waves x 64 thr, 16KB LDS, fence-free). Also keeps R11's
// safe micro-wins: 2-op f2bf, hoisted G gate.
// d_ws holds weights pre-packed into MFMA B-fragment layout (94208 B).

using bf16x8 = __attribute__((ext_vector_type(8))) __bf16;
using f32x4  = __attribute__((ext_vector_type(4))) float;

#define DEV static __device__ __forceinline__

DEV unsigned short f2bf(float f){
  union { float f; unsigned int i; } v; v.f = f;
  return (unsigned short)((v.i + 0x8000u) >> 16);   // round-half-up to bf16
}

// LDS matrices: [rows][64] bf16 (128-B rows), XOR-swizzle byte ^= ((row&7)<<4).
DEV unsigned short* lp(unsigned short* base, int row, int col){
  int byte = (col << 1) ^ ((row & 7) << 4);
  return (unsigned short*)((char*)base + (row << 7) + byte);
}

// A-fragment: lane holds A[row = mt*16 + (lane&15)][k = kt*32 + (lane>>4)*8 + i]
DEV bf16x8 ldA(const unsigned short* base, int mt, int kt, int lane){
  int row = mt*16 + (lane & 15);
  int col = kt*32 + ((lane >> 4) << 3);
  return *(const bf16x8*)lp((unsigned short*)base, row, col);
}
// B-fragment: pre-packed in ws, lane-contiguous 16B
DEV bf16x8 ldB(const unsigned short* w, int frag, int lane){
  return *(const bf16x8*)(w + (size_t)frag*512 + (size_t)lane*8);
}
// Load 8 consecutive frags into a register batch (static indices).
DEV void ld8(bf16x8* W, const unsigned short* w, int base, int lane){
  #pragma unroll
  for (int i = 0; i < 8; ++i) W[i] = ldB(w, base + i, lane);
}
// C/D: col = lane&15, row = mt*16 + (lane>>4)*4 + r
DEV void stC(unsigned short* base, int mt, int nt, f32x4 c, int lane){
  int col  = nt*16 + (lane & 15);
  int row0 = mt*16 + ((lane >> 4) << 2);
  #pragma unroll
  for (int r = 0; r < 4; ++r) *lp(base, row0 + r, col) = f2bf(c[r]);
}
DEV f32x4 MF(bf16x8 a, bf16x8 b, f32x4 c){
  return __builtin_amdgcn_mfma_f32_16x16x32_bf16(a, b, c, 0, 0, 0);
}

DEV void ld16(const unsigned short* base, int row, int col0, float* o){
  uint4 a = *(const uint4*)lp((unsigned short*)base, row, col0);
  uint4 b = *(const uint4*)lp((unsigned short*)base, row, col0 + 8);
  unsigned int w[8] = {a.x, a.y, a.z, a.w, b.x, b.y, b.z, b.w};
  #pragma unroll
  for (int i = 0; i < 8; ++i){
    union { unsigned int u; float f; } lo, hi;
    lo.u = w[i] << 16; hi.u = w[i] & 0xFFFF0000u;
    o[2*i] = lo.f; o[2*i+1] = hi.f;
  }
}
DEV void st16(unsigned short* base, int row, int col0, const float* f){
  unsigned int w[8];
  #pragma unroll
  for (int i = 0; i < 8; ++i)
    w[i] = (unsigned int)f2bf(f[2*i]) | ((unsigned int)f2bf(f[2*i+1]) << 16);
  *(uint4*)lp(base, row, col0)     = make_uint4(w[0], w[1], w[2], w[3]);
  *(uint4*)lp(base, row, col0 + 8) = make_uint4(w[4], w[5], w[6], w[7]);
}

DEV bf16x8 pack8(const float* f){
  union { bf16x8 v; unsigned short u[8]; } r;
  #pragma unroll
  for (int i = 0; i < 8; ++i) r.u[i] = f2bf(f[i]);
  return r.v;
}

// LayerNorm over 64 cols for one 16-row M-tile held as 4 C-frags.
DEV void layer_norm16(f32x4 x[4], const float* g, const float* b, int lane){
  float s[4], s2[4];
  #pragma unroll
  for (int r = 0; r < 4; ++r){
    s[r]  = x[0][r] + x[1][r] + x[2][r] + x[3][r];
    s2[r] = x[0][r]*x[0][r] + x[1][r]*x[1][r] + x[2][r]*x[2][r] + x[3][r]*x[3][r];
  }
  #pragma unroll
  for (int o = 1; o <= 8; o <<= 1){
    #pragma unroll
    for (int r = 0; r < 4; ++r){
      s[r]  += __shfl_xor(s[r],  o);
      s2[r] += __shfl_xor(s2[r], o);
    }
  }
  float mu[4], rs[4];
  #pragma unroll
  for (int r = 0; r < 4; ++r){
    mu[r] = s[r] * (1.f/64.f);
    float var = s2[r] * (1.f/64.f) - mu[r]*mu[r];
    rs[r] = rsqrtf(var + 1e-5f);
  }
  const int cl = lane & 15;
  #pragma unroll
  for (int nt = 0; nt < 4; ++nt){
    float gg = g[nt*16 + cl], bb = b[nt*16 + cl];
    #pragma unroll
    for (int r = 0; r < 4; ++r)
      x[nt][r] = (x[nt][r] - mu[r]) * rs[r] * gg + bb;
  }
}

// ---------------- weight packing (unchanged) ----------------
// 0: pp_w1 (K=8 pad 32, N=64)   base 0,  4 frags
// 1: pp_w2 (K=64,  N=64)        base 4,  8
// 2: in_proj (K=64, N=192)      base 12, 24 (q 12..19, k 20..27, v 28..35)
// 3: out_w (K=64, N=64)         base 36, 8
// 4: ffn_w1 (K=64, N=128)       base 44, 16
// 5: ffn_w2 (K=128, N=64)       base 60, 16
// 6: op_w1 (K=64, N=64)         base 76, 8
// 7: op_w2 (K=64, N=64)         base 84, 8   -> 92 frags total
__global__ void tva_pack_weights(const float* __restrict__ pp_w1, const float* __restrict__ pp_w2,
                                 const float* __restrict__ in_proj_w, const float* __restrict__ out_w,
                                 const float* __restrict__ ffn_w1, const float* __restrict__ ffn_w2,
                                 const float* __restrict__ op_w1, const float* __restrict__ op_w2,
                                 unsigned short* __restrict__ ws)
{
  int b = blockIdx.x, lane = threadIdx.x;
  const float* W; int base, ktiles, K;
  if      (b < 4)  { W = pp_w1;     base = 0;  ktiles = 1; K = 8;   }
  else if (b < 12) { W = pp_w2;     base = 4;  ktiles = 2; K = 64;  }
  else if (b < 36) { W = in_proj_w; base = 12; ktiles = 2; K = 64;  }
  else if (b < 44) { W = out_w;     base = 36; ktiles = 2; K = 64;  }
  else if (b < 60) { W = ffn_w1;    base = 44; ktiles = 2; K = 64;  }
  else if (b < 76) { W = ffn_w2;    base = 60; ktiles = 4; K = 128; }
  else if (b < 84) { W = op_w1;     base = 76; ktiles = 2; K = 64;  }
  else             { W = op_w2;     base = 84; ktiles = 2; K = 64;  }
  int local = b - base;
  int nt = local / ktiles, kt = local % ktiles;
  int n  = nt*16 + (lane & 15);
  int k0 = kt*32 + ((lane >> 4) << 3);
  unsigned short* dst = ws + (size_t)b*512 + (size_t)lane*8;
  #pragma unroll
  for (int i = 0; i < 8; ++i){
    int k = k0 + i;
    float v = (k < K) ? W[(size_t)n*K + k] : 0.0f;
    dst[i] = f2bf(v);
  }
}

// ---------------- main kernel ----------------
__global__ __launch_bounds__(128)
void tva_main(const float* __restrict__ vf, const float* __restrict__ vox,
              const int* __restrict__ num_points,
              const float* __restrict__ pp_b1, const float* __restrict__ pp_b2,
              const float* __restrict__ ipb,  const float* __restrict__ outb,
              const float* __restrict__ ln1g, const float* __restrict__ ln1b,
              const float* __restrict__ f1b,  const float* __restrict__ f2bv,
              const float* __restrict__ ln2g, const float* __restrict__ ln2b,
              const float* __restrict__ o1b,  const float* __restrict__ o2b,
              const unsigned short* __restrict__ wfrag,
              float* __restrict__ out, int nvox)
{
  __shared__ unsigned short smem[2 * 64 * 64];   // 16 KB: 2 waves x 8 KB
  const int tid  = threadIdx.x;
  const int wv   = tid >> 6;
  const int lane = tid & 63;
  unsigned short* X = smem + wv * (64*64);  // rows 0..47: hidden -> tok12 -> K -> V -> ffn-h -> op1-h
  unsigned short* Q = X + 48*64;            // rows 0..15: q -> ctx -> postLN1 -> postLN2

  const int v0 = (blockIdx.x * 2 + wv) * 16;
  if (v0 >= nvox) return;                   // tail waves (no barriers -> safe)
  const int cl = lane & 15;
  const int r0 = (lane >> 4) << 2;

  // ======== Phase A: point aggregation (4 lanes per voxel) ========
  const int vi = lane >> 2, pq = lane & 3;
  const int np = num_points[v0 + vi];
  float cs[8] = {0,0,0,0,0,0,0,0}, hs[8] = {0,0,0,0,0,0,0,0};
  float cc = 0.f, hc = 0.f;
  const float4* vp = (const float4*)(vox + (size_t)(v0 + vi) * 384);
  #pragma unroll
  for (int k = 0; k < 12; ++k){
    int p = pq + (k << 2);
    float4 a = vp[p*2], b = vp[p*2 + 1];
    float pm = (p < np) ? 1.f : 0.f;
    float cm = (b.w > 0.5f) ? pm : 0.f;   // current: flag>0.5 & in-range
    float hm = pm - cm;                   // history: in-range & !current
    cc += cm; hc += hm;
    cs[0] += a.x*cm; cs[1] += a.y*cm; cs[2] += a.z*cm; cs[3] += a.w*cm;
    cs[4] += b.x*cm; cs[5] += b.y*cm; cs[6] += b.z*cm; cs[7] += b.w*cm;
    hs[0] += a.x*hm; hs[1] += a.y*hm; hs[2] += a.z*hm; hs[3] += a.w*hm;
    hs[4] += b.x*hm; hs[5] += b.y*hm; hs[6] += b.z*hm; hs[7] += b.w*hm;
  }
  #pragma unroll
  for (int o = 1; o <= 2; o <<= 1){
    cc += __shfl_xor(cc, o); hc += __shfl_xor(hc, o);
    #pragma unroll
    for (int j = 0; j < 8; ++j){
      cs[j] += __shfl_xor(cs[j], o);
      hs[j] += __shfl_xor(hs[j], o);
    }
  }
  const float icc = 1.f / fmaxf(cc, 1.f);
  const float ihc = 1.f / fmaxf(hc, 1.f);
  const unsigned int myfw = (cc > 0.f ? 1u : 0u) | (hc > 0.f ? 2u : 0u);

  // Build pp-GEMM1 A-fragments in-register (16 shuffles; no LDS staging).
  bf16x8 ac, ah;
  {
    const int src = cl * 4;   // any lane of voxel (lane&15) has the full sums
    float cf[8], hf[8];
    #pragma unroll
    for (int i = 0; i < 8; ++i){
      cf[i] = __shfl(cs[i]*icc, src);
      hf[i] = __shfl(hs[i]*ihc, src);
    }
    union { bf16x8 v; unsigned short u[8]; } rc, rh;
    #pragma unroll
    for (int i = 0; i < 8; ++i){
      rc.u[i] = (lane < 16) ? f2bf(cf[i]) : (unsigned short)0;
      rh.u[i] = (lane < 16) ? f2bf(hf[i]) : (unsigned short)0;
    }
    ac = rc.v; ah = rh.v;
  }

  // Weight prefetch batches: WA/WB alternate, loaded one GEMM-phase ahead.
  bf16x8 WA[8], WB[8];
  #pragma unroll
  for (int i = 0; i < 4; ++i) WA[i] = ldB(wfrag, 0 + i, lane);   // B1 (pp_w1)
  ld8(WB, wfrag, 4, lane);                                       // B2 (pp_w2)

  // ======== Phase B1: point_proj 8->64 relu (weights in WA) ========
  #pragma unroll
  for (int nt = 0; nt < 4; ++nt){
    float bb = pp_b1[nt*16 + cl];
    f32x4 c0 = {bb, bb, bb, bb}, c1 = {bb, bb, bb, bb};
    c0 = MF(ac, WA[nt], c0);
    c1 = MF(ah, WA[nt], c1);
    #pragma unroll
    for (int r = 0; r < 4; ++r){ c0[r] = fmaxf(c0[r], 0.f); c1[r] = fmaxf(c1[r], 0.f); }
    stC(X, 0, nt, c0, lane);   // hidden(cur) rows 0..15
    stC(X, 1, nt, c1, lane);   // hidden(his) rows 16..31
  }
  ld8(WA, wfrag, 12, lane);                                      // prefetch Cq

  // ======== Phase B2: point_proj 64->64 (weights in WB) ========
  {
    bf16x8 hfr[2][2];
    #pragma unroll
    for (int m = 0; m < 2; ++m)
      #pragma unroll
      for (int kt = 0; kt < 2; ++kt) hfr[m][kt] = ldA(X, m, kt, lane);
    // reads precede overwriting stores in program order (per-wave LDS order)
    #pragma unroll
    for (int m = 0; m < 2; ++m){
      #pragma unroll
      for (int nt = 0; nt < 4; ++nt){
        float bb = pp_b2[nt*16 + cl];
        f32x4 c = {bb, bb, bb, bb};
        c = MF(hfr[m][0], WB[nt*2 + 0], c);
        c = MF(hfr[m][1], WB[nt*2 + 1], c);
        stC(X, m, nt, c, lane);   // token1 rows 0..15, token2 rows 16..31
      }
    }
  }
  ld8(WB, wfrag, 20, lane);                                      // prefetch CK

  // ======== Phase C: token0 A-frags + token1/2 A-frags ========
  bf16x8 at[3][2];
  {
    const float* s = vf + (size_t)(v0 + cl) * 64 + ((lane >> 4) << 3);
    #pragma unroll
    for (int kt = 0; kt < 2; ++kt){
      float4 x0 = *(const float4*)(s + kt*32);
      float4 x1 = *(const float4*)(s + kt*32 + 4);
      float f[8] = {x0.x, x0.y, x0.z, x0.w, x1.x, x1.y, x1.z, x1.w};
      at[0][kt] = pack8(f);
    }
    #pragma unroll
    for (int kt = 0; kt < 2; ++kt){
      at[1][kt] = ldA(X, 0, kt, lane);
      at[2][kt] = ldA(X, 1, kt, lane);
    }
  }

  // ======== Phase Cq: q projection (weights in WA), scaled 0.25 -> Q ========
  #pragma unroll
  for (int nt = 0; nt < 4; ++nt){
    float bb = ipb[nt*16 + cl];
    f32x4 c = {bb, bb, bb, bb};
    c = MF(at[0][0], WA[nt*2 + 0], c);
    c = MF(at[0][1], WA[nt*2 + 1], c);
    #pragma unroll
    for (int r = 0; r < 4; ++r) c[r] *= 0.25f;
    stC(Q, 0, nt, c, lane);
  }
  ld8(WA, wfrag, 28, lane);                                      // prefetch C2V

  // ======== Phase CK: K projection, 3 tokens (weights in WB) -> X ========
  #pragma unroll
  for (int m = 0; m < 3; ++m){
    #pragma unroll
    for (int nt = 0; nt < 4; ++nt){
      float bb = ipb[64 + nt*16 + cl];
      f32x4 c = {bb, bb, bb, bb};
      c = MF(at[m][0], WB[nt*2 + 0], c);
      c = MF(at[m][1], WB[nt*2 + 1], c);
      stC(X, m, nt, c, lane);
    }
  }
  ld8(WB, wfrag, 36, lane);                                      // prefetch E

  // ======== Phase D1: scores + softmax (lane = (voxel, head)) ========
  const int av = cl, hh2 = lane >> 4;
  float p0, p1, p2;
  {
    unsigned int fw = (unsigned int)__shfl((int)myfw, av*4);
    bool caZ = (fw & 1u) != 0, hpZ = (fw & 2u) != 0;
    float q[16]; ld16(Q, av, hh2*16, q);
    float sc[3];
    #pragma unroll
    for (int m = 0; m < 3; ++m){
      float kv[16]; ld16(X, m*16 + av, hh2*16, kv);
      float d = 0.f;
      #pragma unroll
      for (int j = 0; j < 16; ++j) d += q[j]*kv[j];
      sc[m] = d;
    }
    float mx = sc[0];
    mx = caZ ? fmaxf(mx, sc[1]) : mx;
    mx = hpZ ? fmaxf(mx, sc[2]) : mx;
    p0 = __expf(sc[0] - mx);
    p1 = caZ ? __expf(sc[1] - mx) : 0.f;
    p2 = hpZ ? __expf(sc[2] - mx) : 0.f;
    float inv = 1.f / (p0 + p1 + p2);
    p0 *= inv; p1 *= inv; p2 *= inv;
  }

  // ======== Phase C2V: V projection (weights in WA) -> X ========
  #pragma unroll
  for (int m = 0; m < 3; ++m){
    #pragma unroll
    for (int nt = 0; nt < 4; ++nt){
      float bb = ipb[128 + nt*16 + cl];
      f32x4 c = {bb, bb, bb, bb};
      c = MF(at[m][0], WA[nt*2 + 0], c);
      c = MF(at[m][1], WA[nt*2 + 1], c);
      stC(X, m, nt, c, lane);
    }
  }
  ld8(WA, wfrag, 44, lane);                                      // prefetch F1a

  // ======== Phase D2: ctx = p . V  -> Q (overwrites q) ========
  {
    float ctx[16];
    float vv[16];
    ld16(X, av, hh2*16, vv);
    #pragma unroll
    for (int j = 0; j < 16; ++j) ctx[j] = p0*vv[j];
    ld16(X, 16 + av, hh2*16, vv);
    #pragma unroll
    for (int j = 0; j < 16; ++j) ctx[j] += p1*vv[j];
    ld16(X, 32 + av, hh2*16, vv);
    #pragma unroll
    for (int j = 0; j < 16; ++j) ctx[j] += p2*vv[j];
    st16(Q, av, hh2*16, ctx);
  }

  // ======== Phase E: attn_out + residual + LN1 (weights in WB) ========
  f32x4 res1[4];
  {
    bf16x8 a0 = ldA(Q, 0, 0, lane), a1 = ldA(Q, 0, 1, lane);
    float rv[16];
    #pragma unroll
    for (int nt = 0; nt < 4; ++nt)
      #pragma unroll
      for (int r = 0; r < 4; ++r)
        rv[nt*4 + r] = vf[(size_t)(v0 + r0 + r)*64 + nt*16 + cl];
    #pragma unroll
    for (int nt = 0; nt < 4; ++nt){
      float bb = outb[nt*16 + cl];
      f32x4 c = {bb, bb, bb, bb};
      c = MF(a0, WB[nt*2 + 0], c);
      c = MF(a1, WB[nt*2 + 1], c);
      #pragma unroll
      for (int r = 0; r < 4; ++r) c[r] += rv[nt*4 + r];
      res1[nt] = c;
    }
    layer_norm16(res1, ln1g, ln1b, lane);
    #pragma unroll
    for (int nt = 0; nt < 4; ++nt) stC(Q, 0, nt, res1[nt], lane);
  }
  // prefetch Fw2a (ffn_w2, k-half 0): frags 60+4nt, 61+4nt
  #pragma unroll
  for (int nt = 0; nt < 4; ++nt){
    WB[2*nt + 0] = ldB(wfrag, 60 + 4*nt + 0, lane);
    WB[2*nt + 1] = ldB(wfrag, 60 + 4*nt + 1, lane);
  }

  // ======== Phase F: FFN (64->128 relu ->64) + residual + LN2 ========
  f32x4 tk2[4];
  {
    bf16x8 a0 = ldA(Q, 0, 0, lane), a1 = ldA(Q, 0, 1, lane);
    #pragma unroll
    for (int nt = 0; nt < 4; ++nt){
      float bb = f2bv[nt*16 + cl];
      tk2[nt] = (f32x4){bb, bb, bb, bb};
    }
    // F1a: h cols 0..63 (weights in WA)
    #pragma unroll
    for (int nt = 0; nt < 4; ++nt){
      float bb = f1b[nt*16 + cl];
      f32x4 c = {bb, bb, bb, bb};
      c = MF(a0, WA[nt*2 + 0], c);
      c = MF(a1, WA[nt*2 + 1], c);
      #pragma unroll
      for (int r = 0; r < 4; ++r) c[r] = fmaxf(c[r], 0.f);
      stC(X, 0, nt, c, lane);
    }
    ld8(WA, wfrag, 52, lane);                                    // prefetch F1b
    // Fw2a (weights in WB)
    {
      bf16x8 h0 = ldA(X, 0, 0, lane), h1 = ldA(X, 0, 1, lane);
      #pragma unroll
      for (int nt = 0; nt < 4; ++nt){
        tk2[nt] = MF(h0, WB[nt*2 + 0], tk2[nt]);
        tk2[nt] = MF(h1, WB[nt*2 + 1], tk2[nt]);
      }
    }
    // prefetch Fw2b: frags 62+4nt, 63+4nt
    #pragma unroll
    for (int nt = 0; nt < 4; ++nt){
      WB[2*nt + 0] = ldB(wfrag, 60 + 4*nt + 2, lane);
      WB[2*nt + 1] = ldB(wfrag, 60 + 4*nt + 3, lane);
    }
    // F1b: h cols 64..127 (weights in WA; h reads above precede these stores)
    #pragma unroll
    for (int nt = 0; nt < 4; ++nt){
      float bb = f1b[(nt + 4)*16 + cl];
      f32x4 c = {bb, bb, bb, bb};
      c = MF(a0, WA[nt*2 + 0], c);
      c = MF(a1, WA[nt*2 + 1], c);
      #pragma unroll
      for (int r = 0; r < 4; ++r) c[r] = fmaxf(c[r], 0.f);
      stC(X, 0, nt, c, lane);
    }
    ld8(WA, wfrag, 76, lane);                                    // prefetch G1
    // Fw2b (weights in WB)
    {
      bf16x8 h0 = ldA(X, 0, 0, lane), h1 = ldA(X, 0, 1, lane);
      #pragma unroll
      for (int nt = 0; nt < 4; ++nt){
        tk2[nt] = MF(h0, WB[nt*2 + 0], tk2[nt]);
        tk2[nt] = MF(h1, WB[nt*2 + 1], tk2[nt]);
      }
    }
    ld8(WB, wfrag, 84, lane);                                    // prefetch G2
    #pragma unroll
    for (int nt = 0; nt < 4; ++nt)
      #pragma unroll
      for (int r = 0; r < 4; ++r) tk2[nt][r] += res1[nt][r];
    layer_norm16(tk2, ln2g, ln2b, lane);
    #pragma unroll
    for (int nt = 0; nt < 4; ++nt) stC(Q, 0, nt, tk2[nt], lane);
  }

  // ======== Phase G: output MLP + gate + final residual ========
  {
    bf16x8 a0 = ldA(Q, 0, 0, lane), a1 = ldA(Q, 0, 1, lane);
    // G1 (weights in WA)
    #pragma unroll
    for (int nt = 0; nt < 4; ++nt){
      float bb = o1b[nt*16 + cl];
      f32x4 c = {bb, bb, bb, bb};
      c = MF(a0, WA[nt*2 + 0], c);
      c = MF(a1, WA[nt*2 + 1], c);
      #pragma unroll
      for (int r = 0; r < 4; ++r) c[r] = fmaxf(c[r], 0.f);
      stC(X, 0, nt, c, lane);
    }
    bf16x8 b0 = ldA(X, 0, 0, lane), b1 = ldA(X, 0, 1, lane);
    // hoist the per-row history gates (repeat across nt)
    float keep[4];
    #pragma unroll
    for (int r = 0; r < 4; ++r){
      unsigned int fw2 = (unsigned int)__shfl((int)myfw, (r0 + r)*4);
      keep[r] = (fw2 & 2u) ? 1.f : 0.f;
    }
    // G2 (weights in WB)
    #pragma unroll
    for (int nt = 0; nt < 4; ++nt){
      float bb = o2b[nt*16 + cl];
      f32x4 c = {bb, bb, bb, bb};
      c = MF(b0, WB[nt*2 + 0], c);
      c = MF(b1, WB[nt*2 + 1], c);
      #pragma unroll
      for (int r = 0; r < 4; ++r){
        size_t idx = (size_t)(v0 + r0 + r)*64 + nt*16 + cl;
        out[idx] = vf[idx] + keep[r] * c[r];
      }
    }
  }
}

extern "C" void kernel_launch(void* const* d_in, const int* in_sizes, int n_in,
                              void* d_out, int out_size, void* d_ws, size_t ws_size,
                              hipStream_t stream)
{
  (void)n_in; (void)out_size; (void)ws_size;
  const float* vf    = (const float*)d_in[0];
  const float* vox   = (const float*)d_in[1];
  const float* pp_w1 = (const float*)d_in[2];
  const float* pp_b1 = (const float*)d_in[3];
  const float* pp_w2 = (const float*)d_in[4];
  const float* pp_b2 = (const float*)d_in[5];
  const float* ipw   = (const float*)d_in[6];
  const float* ipb   = (const float*)d_in[7];
  const float* outw  = (const float*)d_in[8];
  const float* outb  = (const float*)d_in[9];
  const float* ln1g  = (const float*)d_in[10];
  const float* ln1b  = (const float*)d_in[11];
  const float* f1w   = (const float*)d_in[12];
  const float* f1b   = (const float*)d_in[13];
  const float* f2w   = (const float*)d_in[14];
  const float* f2b   = (const float*)d_in[15];
  const float* ln2g  = (const float*)d_in[16];
  const float* ln2b  = (const float*)d_in[17];
  const float* o1w   = (const float*)d_in[18];
  const float* o1b   = (const float*)d_in[19];
  const float* o2w   = (const float*)d_in[20];
  const float* o2b   = (const float*)d_in[21];
  const int*   npts  = (const int*)d_in[22];
  unsigned short* wfrag = (unsigned short*)d_ws;   // 92*512*2 = 94208 B
  float* out = (float*)d_out;

  const int nvox = in_sizes[0] / 64;       // 100000
  const int ngrp = nvox / 16;              // 6250 wave-groups
  const int nblk = (ngrp + 1) / 2;         // 3125 blocks x 2 waves
  tva_pack_weights<<<92, 64, 0, stream>>>(pp_w1, pp_w2, ipw, outw, f1w, f2w, o1w, o2w, wfrag);
  tva_main<<<nblk, 128, 0, stream>>>(vf, vox, npts, pp_b1, pp_b2, ipb, outb,
                                     ln1g, ln1b, f1b, f2b, ln2g, ln2b, o1b, o2b,
                                     wfrag, out, nvox);
}

// Round 13
// 68.546 us; speedup vs baseline: 1.1517x; 1.0455x over previous
//
#include <hip/hip_runtime.h>

// TemporalVoxelAttention — MFMA (bf16) fused.
// R13: DPP CROSS-LANE. R12 showed per-wave latency dropped 1/3 (occ 28.7->
// 19.7%) at IDENTICAL throughput: latency = waves/0.34 exactly across
// R5/6/10/12 -> saturated serialized per-CU resource (~7060 cyc/group).
// Largest pipe component: LDS pipe at ~2650 cyc/group, of which ~120 ops are
// hidden ds_bpermute from __shfl (aggregation reduce 36, LN 64, misc 20).
// Fix: xor1/xor2 reduces are intra-quad -> quad_perm DPP (pure VALU, no LDS
// pipe): replaces 68 bpermutes. Also his = total - cur derived post-reduce.
// Base = R12 (weight prefetch WA/WB, 2 waves x 64 thr, 16KB LDS, fence-free).
// d_ws holds weights pre-packed into MFMA B-fragment layout (94208 B).

using bf16x8 = __attribute__((ext_vector_type(8))) __bf16;
using f32x4  = __attribute__((ext_vector_type(4))) float;

#define DEV static __device__ __forceinline__

// quad_perm DPP add: x + lane-permuted x within each 4-lane quad. Pure VALU.
// 0xB1 = [1,0,3,2] (xor 1), 0x4E = [2,3,0,1] (xor 2).
template<int CTRL>
DEV float dppadd(float x){
  union { float f; int i; } a, b;
  a.f = x;
  b.i = __builtin_amdgcn_update_dpp(0, a.i, CTRL, 0xF, 0xF, true);
  return x + b.f;
}

DEV unsigned short f2bf(float f){
  union { float f; unsigned int i; } v; v.f = f;
  return (unsigned short)((v.i + 0x8000u) >> 16);   // round-half-up to bf16
}

// LDS matrices: [rows][64] bf16 (128-B rows), XOR-swizzle byte ^= ((row&7)<<4).
DEV unsigned short* lp(unsigned short* base, int row, int col){
  int byte = (col << 1) ^ ((row & 7) << 4);
  return (unsigned short*)((char*)base + (row << 7) + byte);
}

// A-fragment: lane holds A[row = mt*16 + (lane&15)][k = kt*32 + (lane>>4)*8 + i]
DEV bf16x8 ldA(const unsigned short* base, int mt, int kt, int lane){
  int row = mt*16 + (lane & 15);
  int col = kt*32 + ((lane >> 4) << 3);
  return *(const bf16x8*)lp((unsigned short*)base, row, col);
}
// B-fragment: pre-packed in ws, lane-contiguous 16B
DEV bf16x8 ldB(const unsigned short* w, int frag, int lane){
  return *(const bf16x8*)(w + (size_t)frag*512 + (size_t)lane*8);
}
// Load 8 consecutive frags into a register batch (static indices).
DEV void ld8(bf16x8* W, const unsigned short* w, int base, int lane){
  #pragma unroll
  for (int i = 0; i < 8; ++i) W[i] = ldB(w, base + i, lane);
}
// C/D: col = lane&15, row = mt*16 + (lane>>4)*4 + r
DEV void stC(unsigned short* base, int mt, int nt, f32x4 c, int lane){
  int col  = nt*16 + (lane & 15);
  int row0 = mt*16 + ((lane >> 4) << 2);
  #pragma unroll
  for (int r = 0; r < 4; ++r) *lp(base, row0 + r, col) = f2bf(c[r]);
}
DEV f32x4 MF(bf16x8 a, bf16x8 b, f32x4 c){
  return __builtin_amdgcn_mfma_f32_16x16x32_bf16(a, b, c, 0, 0, 0);
}

DEV void ld16(const unsigned short* base, int row, int col0, float* o){
  uint4 a = *(const uint4*)lp((unsigned short*)base, row, col0);
  uint4 b = *(const uint4*)lp((unsigned short*)base, row, col0 + 8);
  unsigned int w[8] = {a.x, a.y, a.z, a.w, b.x, b.y, b.z, b.w};
  #pragma unroll
  for (int i = 0; i < 8; ++i){
    union { unsigned int u; float f; } lo, hi;
    lo.u = w[i] << 16; hi.u = w[i] & 0xFFFF0000u;
    o[2*i] = lo.f; o[2*i+1] = hi.f;
  }
}
DEV void st16(unsigned short* base, int row, int col0, const float* f){
  unsigned int w[8];
  #pragma unroll
  for (int i = 0; i < 8; ++i)
    w[i] = (unsigned int)f2bf(f[2*i]) | ((unsigned int)f2bf(f[2*i+1]) << 16);
  *(uint4*)lp(base, row, col0)     = make_uint4(w[0], w[1], w[2], w[3]);
  *(uint4*)lp(base, row, col0 + 8) = make_uint4(w[4], w[5], w[6], w[7]);
}

DEV bf16x8 pack8(const float* f){
  union { bf16x8 v; unsigned short u[8]; } r;
  #pragma unroll
  for (int i = 0; i < 8; ++i) r.u[i] = f2bf(f[i]);
  return r.v;
}

// LayerNorm over 64 cols for one 16-row M-tile held as 4 C-frags.
// xor1/xor2 stages via quad_perm DPP (VALU); xor4/xor8 via shfl.
DEV void layer_norm16(f32x4 x[4], const float* g, const float* b, int lane){
  float s[4], s2[4];
  #pragma unroll
  for (int r = 0; r < 4; ++r){
    s[r]  = x[0][r] + x[1][r] + x[2][r] + x[3][r];
    s2[r] = x[0][r]*x[0][r] + x[1][r]*x[1][r] + x[2][r]*x[2][r] + x[3][r]*x[3][r];
  }
  #pragma unroll
  for (int r = 0; r < 4; ++r){
    s[r]  = dppadd<0xB1>(s[r]);   s2[r] = dppadd<0xB1>(s2[r]);
    s[r]  = dppadd<0x4E>(s[r]);   s2[r] = dppadd<0x4E>(s2[r]);
  }
  #pragma unroll
  for (int o = 4; o <= 8; o <<= 1){
    #pragma unroll
    for (int r = 0; r < 4; ++r){
      s[r]  += __shfl_xor(s[r],  o);
      s2[r] += __shfl_xor(s2[r], o);
    }
  }
  float mu[4], rs[4];
  #pragma unroll
  for (int r = 0; r < 4; ++r){
    mu[r] = s[r] * (1.f/64.f);
    float var = s2[r] * (1.f/64.f) - mu[r]*mu[r];
    rs[r] = rsqrtf(var + 1e-5f);
  }
  const int cl = lane & 15;
  #pragma unroll
  for (int nt = 0; nt < 4; ++nt){
    float gg = g[nt*16 + cl], bb = b[nt*16 + cl];
    #pragma unroll
    for (int r = 0; r < 4; ++r)
      x[nt][r] = (x[nt][r] - mu[r]) * rs[r] * gg + bb;
  }
}

// ---------------- weight packing (unchanged) ----------------
// 0: pp_w1 (K=8 pad 32, N=64)   base 0,  4 frags
// 1: pp_w2 (K=64,  N=64)        base 4,  8
// 2: in_proj (K=64, N=192)      base 12, 24 (q 12..19, k 20..27, v 28..35)
// 3: out_w (K=64, N=64)         base 36, 8
// 4: ffn_w1 (K=64, N=128)       base 44, 16
// 5: ffn_w2 (K=128, N=64)       base 60, 16
// 6: op_w1 (K=64, N=64)         base 76, 8
// 7: op_w2 (K=64, N=64)         base 84, 8   -> 92 frags total
__global__ void tva_pack_weights(const float* __restrict__ pp_w1, const float* __restrict__ pp_w2,
                                 const float* __restrict__ in_proj_w, const float* __restrict__ out_w,
                                 const float* __restrict__ ffn_w1, const float* __restrict__ ffn_w2,
                                 const float* __restrict__ op_w1, const float* __restrict__ op_w2,
                                 unsigned short* __restrict__ ws)
{
  int b = blockIdx.x, lane = threadIdx.x;
  const float* W; int base, ktiles, K;
  if      (b < 4)  { W = pp_w1;     base = 0;  ktiles = 1; K = 8;   }
  else if (b < 12) { W = pp_w2;     base = 4;  ktiles = 2; K = 64;  }
  else if (b < 36) { W = in_proj_w; base = 12; ktiles = 2; K = 64;  }
  else if (b < 44) { W = out_w;     base = 36; ktiles = 2; K = 64;  }
  else if (b < 60) { W = ffn_w1;    base = 44; ktiles = 2; K = 64;  }
  else if (b < 76) { W = ffn_w2;    base = 60; ktiles = 4; K = 128; }
  else if (b < 84) { W = op_w1;     base = 76; ktiles = 2; K = 64;  }
  else             { W = op_w2;     base = 84; ktiles = 2; K = 64;  }
  int local = b - base;
  int nt = local / ktiles, kt = local % ktiles;
  int n  = nt*16 + (lane & 15);
  int k0 = kt*32 + ((lane >> 4) << 3);
  unsigned short* dst = ws + (size_t)b*512 + (size_t)lane*8;
  #pragma unroll
  for (int i = 0; i < 8; ++i){
    int k = k0 + i;
    float v = (k < K) ? W[(size_t)n*K + k] : 0.0f;
    dst[i] = f2bf(v);
  }
}

// ---------------- main kernel ----------------
__global__ __launch_bounds__(128)
void tva_main(const float* __restrict__ vf, const float* __restrict__ vox,
              const int* __restrict__ num_points,
              const float* __restrict__ pp_b1, const float* __restrict__ pp_b2,
              const float* __restrict__ ipb,  const float* __restrict__ outb,
              const float* __restrict__ ln1g, const float* __restrict__ ln1b,
              const float* __restrict__ f1b,  const float* __restrict__ f2bv,
              const float* __restrict__ ln2g, const float* __restrict__ ln2b,
              const float* __restrict__ o1b,  const float* __restrict__ o2b,
              const unsigned short* __restrict__ wfrag,
              float* __restrict__ out, int nvox)
{
  __shared__ unsigned short smem[2 * 64 * 64];   // 16 KB: 2 waves x 8 KB
  const int tid  = threadIdx.x;
  const int wv   = tid >> 6;
  const int lane = tid & 63;
  unsigned short* X = smem + wv * (64*64);  // rows 0..47: hidden -> tok12 -> K -> V -> ffn-h -> op1-h
  unsigned short* Q = X + 48*64;            // rows 0..15: q -> ctx -> postLN1 -> postLN2

  const int v0 = (blockIdx.x * 2 + wv) * 16;
  if (v0 >= nvox) return;                   // tail waves (no barriers -> safe)
  const int cl = lane & 15;
  const int r0 = (lane >> 4) << 2;

  // ======== Phase A: point aggregation (4 lanes per voxel) ========
  // Accumulate TOTAL (valid) and CURRENT; history = total - current post-reduce.
  const int vi = lane >> 2, pq = lane & 3;
  const int np = num_points[v0 + vi];
  float ts[8] = {0,0,0,0,0,0,0,0}, cs[8] = {0,0,0,0,0,0,0,0};
  float tc = 0.f, cc = 0.f;
  const float4* vp = (const float4*)(vox + (size_t)(v0 + vi) * 384);
  #pragma unroll
  for (int k = 0; k < 12; ++k){
    int p = pq + (k << 2);
    float4 a = vp[p*2], b = vp[p*2 + 1];
    float pm = (p < np) ? 1.f : 0.f;
    float cm = (b.w > 0.5f) ? pm : 0.f;   // current: flag>0.5 & in-range
    tc += pm; cc += cm;
    ts[0] += a.x*pm; ts[1] += a.y*pm; ts[2] += a.z*pm; ts[3] += a.w*pm;
    ts[4] += b.x*pm; ts[5] += b.y*pm; ts[6] += b.z*pm; ts[7] += b.w*pm;
    cs[0] += a.x*cm; cs[1] += a.y*cm; cs[2] += a.z*cm; cs[3] += a.w*cm;
    cs[4] += b.x*cm; cs[5] += b.y*cm; cs[6] += b.z*cm; cs[7] += b.w*cm;
  }
  // intra-quad butterfly via DPP (pure VALU, no LDS pipe)
  tc = dppadd<0xB1>(tc); cc = dppadd<0xB1>(cc);
  #pragma unroll
  for (int j = 0; j < 8; ++j){ ts[j] = dppadd<0xB1>(ts[j]); cs[j] = dppadd<0xB1>(cs[j]); }
  tc = dppadd<0x4E>(tc); cc = dppadd<0x4E>(cc);
  #pragma unroll
  for (int j = 0; j < 8; ++j){ ts[j] = dppadd<0x4E>(ts[j]); cs[j] = dppadd<0x4E>(cs[j]); }

  const float hc  = tc - cc;
  const float icc = 1.f / fmaxf(cc, 1.f);
  const float ihc = 1.f / fmaxf(hc, 1.f);
  const unsigned int myfw = (cc > 0.f ? 1u : 0u) | (hc > 0.f ? 2u : 0u);

  // Build pp-GEMM1 A-fragments in-register (16 bpermutes; no LDS staging).
  bf16x8 ac, ah;
  {
    const int src = cl * 4;   // any lane of voxel (lane&15) has the full sums
    float cf[8], hf[8];
    #pragma unroll
    for (int i = 0; i < 8; ++i){
      cf[i] = __shfl(cs[i]*icc, src);
      hf[i] = __shfl((ts[i] - cs[i])*ihc, src);
    }
    union { bf16x8 v; unsigned short u[8]; } rc, rh;
    #pragma unroll
    for (int i = 0; i < 8; ++i){
      rc.u[i] = (lane < 16) ? f2bf(cf[i]) : (unsigned short)0;
      rh.u[i] = (lane < 16) ? f2bf(hf[i]) : (unsigned short)0;
    }
    ac = rc.v; ah = rh.v;
  }

  // Weight prefetch batches: WA/WB alternate, loaded one GEMM-phase ahead.
  bf16x8 WA[8], WB[8];
  #pragma unroll
  for (int i = 0; i < 4; ++i) WA[i] = ldB(wfrag, 0 + i, lane);   // B1 (pp_w1)
  ld8(WB, wfrag, 4, lane);                                       // B2 (pp_w2)

  // ======== Phase B1: point_proj 8->64 relu (weights in WA) ========
  #pragma unroll
  for (int nt = 0; nt < 4; ++nt){
    float bb = pp_b1[nt*16 + cl];
    f32x4 c0 = {bb, bb, bb, bb}, c1 = {bb, bb, bb, bb};
    c0 = MF(ac, WA[nt], c0);
    c1 = MF(ah, WA[nt], c1);
    #pragma unroll
    for (int r = 0; r < 4; ++r){ c0[r] = fmaxf(c0[r], 0.f); c1[r] = fmaxf(c1[r], 0.f); }
    stC(X, 0, nt, c0, lane);   // hidden(cur) rows 0..15
    stC(X, 1, nt, c1, lane);   // hidden(his) rows 16..31
  }
  ld8(WA, wfrag, 12, lane);                                      // prefetch Cq

  // ======== Phase B2: point_proj 64->64 (weights in WB) ========
  {
    bf16x8 hfr[2][2];
    #pragma unroll
    for (int m = 0; m < 2; ++m)
      #pragma unroll
      for (int kt = 0; kt < 2; ++kt) hfr[m][kt] = ldA(X, m, kt, lane);
    // reads precede overwriting stores in program order (per-wave LDS order)
    #pragma unroll
    for (int m = 0; m < 2; ++m){
      #pragma unroll
      for (int nt = 0; nt < 4; ++nt){
        float bb = pp_b2[nt*16 + cl];
        f32x4 c = {bb, bb, bb, bb};
        c = MF(hfr[m][0], WB[nt*2 + 0], c);
        c = MF(hfr[m][1], WB[nt*2 + 1], c);
        stC(X, m, nt, c, lane);   // token1 rows 0..15, token2 rows 16..31
      }
    }
  }
  ld8(WB, wfrag, 20, lane);                                      // prefetch CK

  // ======== Phase C: token0 A-frags + token1/2 A-frags ========
  bf16x8 at[3][2];
  {
    const float* s = vf + (size_t)(v0 + cl) * 64 + ((lane >> 4) << 3);
    #pragma unroll
    for (int kt = 0; kt < 2; ++kt){
      float4 x0 = *(const float4*)(s + kt*32);
      float4 x1 = *(const float4*)(s + kt*32 + 4);
      float f[8] = {x0.x, x0.y, x0.z, x0.w, x1.x, x1.y, x1.z, x1.w};
      at[0][kt] = pack8(f);
    }
    #pragma unroll
    for (int kt = 0; kt < 2; ++kt){
      at[1][kt] = ldA(X, 0, kt, lane);
      at[2][kt] = ldA(X, 1, kt, lane);
    }
  }

  // ======== Phase Cq: q projection (weights in WA), scaled 0.25 -> Q ========
  #pragma unroll
  for (int nt = 0; nt < 4; ++nt){
    float bb = ipb[nt*16 + cl];
    f32x4 c = {bb, bb, bb, bb};
    c = MF(at[0][0], WA[nt*2 + 0], c);
    c = MF(at[0][1], WA[nt*2 + 1], c);
    #pragma unroll
    for (int r = 0; r < 4; ++r) c[r] *= 0.25f;
    stC(Q, 0, nt, c, lane);
  }
  ld8(WA, wfrag, 28, lane);                                      // prefetch C2V

  // ======== Phase CK: K projection, 3 tokens (weights in WB) -> X ========
  #pragma unroll
  for (int m = 0; m < 3; ++m){
    #pragma unroll
    for (int nt = 0; nt < 4; ++nt){
      float bb = ipb[64 + nt*16 + cl];
      f32x4 c = {bb, bb, bb, bb};
      c = MF(at[m][0], WB[nt*2 + 0], c);
      c = MF(at[m][1], WB[nt*2 + 1], c);
      stC(X, m, nt, c, lane);
    }
  }
  ld8(WB, wfrag, 36, lane);                                      // prefetch E

  // ======== Phase D1: scores + softmax (lane = (voxel, head)) ========
  const int av = cl, hh2 = lane >> 4;
  float p0, p1, p2;
  {
    unsigned int fw = (unsigned int)__shfl((int)myfw, av*4);
    bool caZ = (fw & 1u) != 0, hpZ = (fw & 2u) != 0;
    float q[16]; ld16(Q, av, hh2*16, q);
    float sc[3];
    #pragma unroll
    for (int m = 0; m < 3; ++m){
      float kv[16]; ld16(X, m*16 + av, hh2*16, kv);
      float d = 0.f;
      #pragma unroll
      for (int j = 0; j < 16; ++j) d += q[j]*kv[j];
      sc[m] = d;
    }
    float mx = sc[0];
    mx = caZ ? fmaxf(mx, sc[1]) : mx;
    mx = hpZ ? fmaxf(mx, sc[2]) : mx;
    p0 = __expf(sc[0] - mx);
    p1 = caZ ? __expf(sc[1] - mx) : 0.f;
    p2 = hpZ ? __expf(sc[2] - mx) : 0.f;
    float inv = 1.f / (p0 + p1 + p2);
    p0 *= inv; p1 *= inv; p2 *= inv;
  }

  // ======== Phase C2V: V projection (weights in WA) -> X ========
  #pragma unroll
  for (int m = 0; m < 3; ++m){
    #pragma unroll
    for (int nt = 0; nt < 4; ++nt){
      float bb = ipb[128 + nt*16 + cl];
      f32x4 c = {bb, bb, bb, bb};
      c = MF(at[m][0], WA[nt*2 + 0], c);
      c = MF(at[m][1], WA[nt*2 + 1], c);
      stC(X, m, nt, c, lane);
    }
  }
  ld8(WA, wfrag, 44, lane);                                      // prefetch F1a

  // ======== Phase D2: ctx = p . V  -> Q (overwrites q) ========
  {
    float ctx[16];
    float vv[16];
    ld16(X, av, hh2*16, vv);
    #pragma unroll
    for (int j = 0; j < 16; ++j) ctx[j] = p0*vv[j];
    ld16(X, 16 + av, hh2*16, vv);
    #pragma unroll
    for (int j = 0; j < 16; ++j) ctx[j] += p1*vv[j];
    ld16(X, 32 + av, hh2*16, vv);
    #pragma unroll
    for (int j = 0; j < 16; ++j) ctx[j] += p2*vv[j];
    st16(Q, av, hh2*16, ctx);
  }

  // ======== Phase E: attn_out + residual + LN1 (weights in WB) ========
  f32x4 res1[4];
  {
    bf16x8 a0 = ldA(Q, 0, 0, lane), a1 = ldA(Q, 0, 1, lane);
    float rv[16];
    #pragma unroll
    for (int nt = 0; nt < 4; ++nt)
      #pragma unroll
      for (int r = 0; r < 4; ++r)
        rv[nt*4 + r] = vf[(size_t)(v0 + r0 + r)*64 + nt*16 + cl];
    #pragma unroll
    for (int nt = 0; nt < 4; ++nt){
      float bb = outb[nt*16 + cl];
      f32x4 c = {bb, bb, bb, bb};
      c = MF(a0, WB[nt*2 + 0], c);
      c = MF(a1, WB[nt*2 + 1], c);
      #pragma unroll
      for (int r = 0; r < 4; ++r) c[r] += rv[nt*4 + r];
      res1[nt] = c;
    }
    layer_norm16(res1, ln1g, ln1b, lane);
    #pragma unroll
    for (int nt = 0; nt < 4; ++nt) stC(Q, 0, nt, res1[nt], lane);
  }
  // prefetch Fw2a (ffn_w2, k-half 0): frags 60+4nt, 61+4nt
  #pragma unroll
  for (int nt = 0; nt < 4; ++nt){
    WB[2*nt + 0] = ldB(wfrag, 60 + 4*nt + 0, lane);
    WB[2*nt + 1] = ldB(wfrag, 60 + 4*nt + 1, lane);
  }

  // ======== Phase F: FFN (64->128 relu ->64) + residual + LN2 ========
  f32x4 tk2[4];
  {
    bf16x8 a0 = ldA(Q, 0, 0, lane), a1 = ldA(Q, 0, 1, lane);
    #pragma unroll
    for (int nt = 0; nt < 4; ++nt){
      float bb = f2bv[nt*16 + cl];
      tk2[nt] = (f32x4){bb, bb, bb, bb};
    }
    // F1a: h cols 0..63 (weights in WA)
    #pragma unroll
    for (int nt = 0; nt < 4; ++nt){
      float bb = f1b[nt*16 + cl];
      f32x4 c = {bb, bb, bb, bb};
      c = MF(a0, WA[nt*2 + 0], c);
      c = MF(a1, WA[nt*2 + 1], c);
      #pragma unroll
      for (int r = 0; r < 4; ++r) c[r] = fmaxf(c[r], 0.f);
      stC(X, 0, nt, c, lane);
    }
    ld8(WA, wfrag, 52, lane);                                    // prefetch F1b
    // Fw2a (weights in WB)
    {
      bf16x8 h0 = ldA(X, 0, 0, lane), h1 = ldA(X, 0, 1, lane);
      #pragma unroll
      for (int nt = 0; nt < 4; ++nt){
        tk2[nt] = MF(h0, WB[nt*2 + 0], tk2[nt]);
        tk2[nt] = MF(h1, WB[nt*2 + 1], tk2[nt]);
      }
    }
    // prefetch Fw2b: frags 62+4nt, 63+4nt
    #pragma unroll
    for (int nt = 0; nt < 4; ++nt){
      WB[2*nt + 0] = ldB(wfrag, 60 + 4*nt + 2, lane);
      WB[2*nt + 1] = ldB(wfrag, 60 + 4*nt + 3, lane);
    }
    // F1b: h cols 64..127 (weights in WA; h reads above precede these stores)
    #pragma unroll
    for (int nt = 0; nt < 4; ++nt){
      float bb = f1b[(nt + 4)*16 + cl];
      f32x4 c = {bb, bb, bb, bb};
      c = MF(a0, WA[nt*2 + 0], c);
      c = MF(a1, WA[nt*2 + 1], c);
      #pragma unroll
      for (int r = 0; r < 4; ++r) c[r] = fmaxf(c[r], 0.f);
      stC(X, 0, nt, c, lane);
    }
    ld8(WA, wfrag, 76, lane);                                    // prefetch G1
    // Fw2b (weights in WB)
    {
      bf16x8 h0 = ldA(X, 0, 0, lane), h1 = ldA(X, 0, 1, lane);
      #pragma unroll
      for (int nt = 0; nt < 4; ++nt){
        tk2[nt] = MF(h0, WB[nt*2 + 0], tk2[nt]);
        tk2[nt] = MF(h1, WB[nt*2 + 1], tk2[nt]);
      }
    }
    ld8(WB, wfrag, 84, lane);                                    // prefetch G2
    #pragma unroll
    for (int nt = 0; nt < 4; ++nt)
      #pragma unroll
      for (int r = 0; r < 4; ++r) tk2[nt][r] += res1[nt][r];
    layer_norm16(tk2, ln2g, ln2b, lane);
    #pragma unroll
    for (int nt = 0; nt < 4; ++nt) stC(Q, 0, nt, tk2[nt], lane);
  }

  // ======== Phase G: output MLP + gate + final residual ========
  {
    bf16x8 a0 = ldA(Q, 0, 0, lane), a1 = ldA(Q, 0, 1, lane);
    // G1 (weights in WA)
    #pragma unroll
    for (int nt = 0; nt < 4; ++nt){
      float bb = o1b[nt*16 + cl];
      f32x4 c = {bb, bb, bb, bb};
      c = MF(a0, WA[nt*2 + 0], c);
      c = MF(a1, WA[nt*2 + 1], c);
      #pragma unroll
      for (int r = 0; r < 4; ++r) c[r] = fmaxf(c[r], 0.f);
      stC(X, 0, nt, c, lane);
    }
    bf16x8 b0 = ldA(X, 0, 0, lane), b1 = ldA(X, 0, 1, lane);
    // hoist the per-row history gates (repeat across nt)
    float keep[4];
    #pragma unroll
    for (int r = 0; r < 4; ++r){
      unsigned int fw2 = (unsigned int)__shfl((int)myfw, (r0 + r)*4);
      keep[r] = (fw2 & 2u) ? 1.f : 0.f;
    }
    // G2 (weights in WB)
    #pragma unroll
    for (int nt = 0; nt < 4; ++nt){
      float bb = o2b[nt*16 + cl];
      f32x4 c = {bb, bb, bb, bb};
      c = MF(b0, WB[nt*2 + 0], c);
      c = MF(b1, WB[nt*2 + 1], c);
      #pragma unroll
      for (int r = 0; r < 4; ++r){
        size_t idx = (size_t)(v0 + r0 + r)*64 + nt*16 + cl;
        out[idx] = vf[idx] + keep[r] * c[r];
      }
    }
  }
}

extern "C" void kernel_launch(void* const* d_in, const int* in_sizes, int n_in,
                              void* d_out, int out_size, void* d_ws, size_t ws_size,
                              hipStream_t stream)
{
  (void)n_in; (void)out_size; (void)ws_size;
  const float* vf    = (const float*)d_in[0];
  const float* vox   = (const float*)d_in[1];
  const float* pp_w1 = (const float*)d_in[2];
  const float* pp_b1 = (const float*)d_in[3];
  const float* pp_w2 = (const float*)d_in[4];
  const float* pp_b2 = (const float*)d_in[5];
  const float* ipw   = (const float*)d_in[6];
  const float* ipb   = (const float*)d_in[7];
  const float* outw  = (const float*)d_in[8];
  const float* outb  = (const float*)d_in[9];
  const float* ln1g  = (const float*)d_in[10];
  const float* ln1b  = (const float*)d_in[11];
  const float* f1w   = (const float*)d_in[12];
  const float* f1b   = (const float*)d_in[13];
  const float* f2w   = (const float*)d_in[14];
  const float* f2b   = (const float*)d_in[15];
  const float* ln2g  = (const float*)d_in[16];
  const float* ln2b  = (const float*)d_in[17];
  const float* o1w   = (const float*)d_in[18];
  const float* o1b   = (const float*)d_in[19];
  const float* o2w   = (const float*)d_in[20];
  const float* o2b   = (const float*)d_in[21];
  const int*   npts  = (const int*)d_in[22];
  unsigned short* wfrag = (unsigned short*)d_ws;   // 92*512*2 = 94208 B
  float* out = (float*)d_out;

  const int nvox = in_sizes[0] / 64;       // 100000
  const int ngrp = nvox / 16;              // 6250 wave-groups
  const int nblk = (ngrp + 1) / 2;         // 3125 blocks x 2 waves
  tva_pack_weights<<<92, 64, 0, stream>>>(pp_w1, pp_w2, ipw, outw, f1w, f2w, o1w, o2w, wfrag);
  tva_main<<<nblk, 128, 0, stream>>>(vf, vox, npts, pp_b1, pp_b2, ipb, outb,
                                     ln1g, ln1b, f1b, f2b, ln2g, ln2b, o1b, o2b,
                                     wfrag, out, nvox);
}

// Round 14
// 68.355 us; speedup vs baseline: 1.1549x; 1.0028x over previous
//
#include <hip/hip_runtime.h>

// TemporalVoxelAttention — MFMA (bf16) fused.
// R14: finish cross-lane eviction. R13 measured ~4.7 cyc per removed
// LDS-pipe/cross-lane op (320 cyc for 68 bpermutes) — serialized-op model
// with a coefficient. Remaining removable: LN's xor4/xor8 stages (32 shfl
// bpermutes) -> DPP row_ror:4/row_ror:8 rotate-accumulate (after quad stages
// every quad holds its quad-sum, so two rotations sum all 4 quads on every
// lane, pure VALU). Also total_count == num_points exactly (randint<48) ->
// delete tc accumulator (12 adds + 2 DPS). Base = R13 (weight prefetch,
// DPP quad reduce, 2 waves x 64 thr, 16KB LDS, fence-free).
// d_ws holds weights pre-packed into MFMA B-fragment layout (94208 B).

using bf16x8 = __attribute__((ext_vector_type(8))) __bf16;
using f32x4  = __attribute__((ext_vector_type(4))) float;

#define DEV static __device__ __forceinline__

// DPP add: x + lane-permuted x. Pure VALU, no LDS pipe.
// quad_perm 0xB1 = xor1, 0x4E = xor2; row_ror:4 = 0x124, row_ror:8 = 0x128
// (rotation within each 16-lane row).
template<int CTRL>
DEV float dppadd(float x){
  union { float f; int i; } a, b;
  a.f = x;
  b.i = __builtin_amdgcn_update_dpp(0, a.i, CTRL, 0xF, 0xF, true);
  return x + b.f;
}

DEV unsigned short f2bf(float f){
  union { float f; unsigned int i; } v; v.f = f;
  return (unsigned short)((v.i + 0x8000u) >> 16);   // round-half-up to bf16
}

// LDS matrices: [rows][64] bf16 (128-B rows), XOR-swizzle byte ^= ((row&7)<<4).
DEV unsigned short* lp(unsigned short* base, int row, int col){
  int byte = (col << 1) ^ ((row & 7) << 4);
  return (unsigned short*)((char*)base + (row << 7) + byte);
}

// A-fragment: lane holds A[row = mt*16 + (lane&15)][k = kt*32 + (lane>>4)*8 + i]
DEV bf16x8 ldA(const unsigned short* base, int mt, int kt, int lane){
  int row = mt*16 + (lane & 15);
  int col = kt*32 + ((lane >> 4) << 3);
  return *(const bf16x8*)lp((unsigned short*)base, row, col);
}
// B-fragment: pre-packed in ws, lane-contiguous 16B
DEV bf16x8 ldB(const unsigned short* w, int frag, int lane){
  return *(const bf16x8*)(w + (size_t)frag*512 + (size_t)lane*8);
}
// Load 8 consecutive frags into a register batch (static indices).
DEV void ld8(bf16x8* W, const unsigned short* w, int base, int lane){
  #pragma unroll
  for (int i = 0; i < 8; ++i) W[i] = ldB(w, base + i, lane);
}
// C/D: col = lane&15, row = mt*16 + (lane>>4)*4 + r
DEV void stC(unsigned short* base, int mt, int nt, f32x4 c, int lane){
  int col  = nt*16 + (lane & 15);
  int row0 = mt*16 + ((lane >> 4) << 2);
  #pragma unroll
  for (int r = 0; r < 4; ++r) *lp(base, row0 + r, col) = f2bf(c[r]);
}
DEV f32x4 MF(bf16x8 a, bf16x8 b, f32x4 c){
  return __builtin_amdgcn_mfma_f32_16x16x32_bf16(a, b, c, 0, 0, 0);
}

DEV void ld16(const unsigned short* base, int row, int col0, float* o){
  uint4 a = *(const uint4*)lp((unsigned short*)base, row, col0);
  uint4 b = *(const uint4*)lp((unsigned short*)base, row, col0 + 8);
  unsigned int w[8] = {a.x, a.y, a.z, a.w, b.x, b.y, b.z, b.w};
  #pragma unroll
  for (int i = 0; i < 8; ++i){
    union { unsigned int u; float f; } lo, hi;
    lo.u = w[i] << 16; hi.u = w[i] & 0xFFFF0000u;
    o[2*i] = lo.f; o[2*i+1] = hi.f;
  }
}
DEV void st16(unsigned short* base, int row, int col0, const float* f){
  unsigned int w[8];
  #pragma unroll
  for (int i = 0; i < 8; ++i)
    w[i] = (unsigned int)f2bf(f[2*i]) | ((unsigned int)f2bf(f[2*i+1]) << 16);
  *(uint4*)lp(base, row, col0)     = make_uint4(w[0], w[1], w[2], w[3]);
  *(uint4*)lp(base, row, col0 + 8) = make_uint4(w[4], w[5], w[6], w[7]);
}

DEV bf16x8 pack8(const float* f){
  union { bf16x8 v; unsigned short u[8]; } r;
  #pragma unroll
  for (int i = 0; i < 8; ++i) r.u[i] = f2bf(f[i]);
  return r.v;
}

// LayerNorm over 64 cols for one 16-row M-tile held as 4 C-frags.
// xor1/xor2 via quad_perm DPP; cross-quad via row_ror:4 + row_ror:8 DPP
// (all lanes of a quad hold the quad-sum, so rotate-accumulate sums the 4
// quads of the 16-lane row on every lane). Zero LDS-pipe ops.
DEV void layer_norm16(f32x4 x[4], const float* g, const float* b, int lane){
  float s[4], s2[4];
  #pragma unroll
  for (int r = 0; r < 4; ++r){
    s[r]  = x[0][r] + x[1][r] + x[2][r] + x[3][r];
    s2[r] = x[0][r]*x[0][r] + x[1][r]*x[1][r] + x[2][r]*x[2][r] + x[3][r]*x[3][r];
  }
  #pragma unroll
  for (int r = 0; r < 4; ++r){
    s[r]  = dppadd<0xB1>(s[r]);    s2[r] = dppadd<0xB1>(s2[r]);
    s[r]  = dppadd<0x4E>(s[r]);    s2[r] = dppadd<0x4E>(s2[r]);
    s[r]  = dppadd<0x124>(s[r]);   s2[r] = dppadd<0x124>(s2[r]);
    s[r]  = dppadd<0x128>(s[r]);   s2[r] = dppadd<0x128>(s2[r]);
  }
  float mu[4], rs[4];
  #pragma unroll
  for (int r = 0; r < 4; ++r){
    mu[r] = s[r] * (1.f/64.f);
    float var = s2[r] * (1.f/64.f) - mu[r]*mu[r];
    rs[r] = rsqrtf(var + 1e-5f);
  }
  const int cl = lane & 15;
  #pragma unroll
  for (int nt = 0; nt < 4; ++nt){
    float gg = g[nt*16 + cl], bb = b[nt*16 + cl];
    #pragma unroll
    for (int r = 0; r < 4; ++r)
      x[nt][r] = (x[nt][r] - mu[r]) * rs[r] * gg + bb;
  }
}

// ---------------- weight packing (unchanged) ----------------
// 0: pp_w1 (K=8 pad 32, N=64)   base 0,  4 frags
// 1: pp_w2 (K=64,  N=64)        base 4,  8
// 2: in_proj (K=64, N=192)      base 12, 24 (q 12..19, k 20..27, v 28..35)
// 3: out_w (K=64, N=64)         base 36, 8
// 4: ffn_w1 (K=64, N=128)       base 44, 16
// 5: ffn_w2 (K=128, N=64)       base 60, 16
// 6: op_w1 (K=64, N=64)         base 76, 8
// 7: op_w2 (K=64, N=64)         base 84, 8   -> 92 frags total
__global__ void tva_pack_weights(const float* __restrict__ pp_w1, const float* __restrict__ pp_w2,
                                 const float* __restrict__ in_proj_w, const float* __restrict__ out_w,
                                 const float* __restrict__ ffn_w1, const float* __restrict__ ffn_w2,
                                 const float* __restrict__ op_w1, const float* __restrict__ op_w2,
                                 unsigned short* __restrict__ ws)
{
  int b = blockIdx.x, lane = threadIdx.x;
  const float* W; int base, ktiles, K;
  if      (b < 4)  { W = pp_w1;     base = 0;  ktiles = 1; K = 8;   }
  else if (b < 12) { W = pp_w2;     base = 4;  ktiles = 2; K = 64;  }
  else if (b < 36) { W = in_proj_w; base = 12; ktiles = 2; K = 64;  }
  else if (b < 44) { W = out_w;     base = 36; ktiles = 2; K = 64;  }
  else if (b < 60) { W = ffn_w1;    base = 44; ktiles = 2; K = 64;  }
  else if (b < 76) { W = ffn_w2;    base = 60; ktiles = 4; K = 128; }
  else if (b < 84) { W = op_w1;     base = 76; ktiles = 2; K = 64;  }
  else             { W = op_w2;     base = 84; ktiles = 2; K = 64;  }
  int local = b - base;
  int nt = local / ktiles, kt = local % ktiles;
  int n  = nt*16 + (lane & 15);
  int k0 = kt*32 + ((lane >> 4) << 3);
  unsigned short* dst = ws + (size_t)b*512 + (size_t)lane*8;
  #pragma unroll
  for (int i = 0; i < 8; ++i){
    int k = k0 + i;
    float v = (k < K) ? W[(size_t)n*K + k] : 0.0f;
    dst[i] = f2bf(v);
  }
}

// ---------------- main kernel ----------------
__global__ __launch_bounds__(128)
void tva_main(const float* __restrict__ vf, const float* __restrict__ vox,
              const int* __restrict__ num_points,
              const float* __restrict__ pp_b1, const float* __restrict__ pp_b2,
              const float* __restrict__ ipb,  const float* __restrict__ outb,
              const float* __restrict__ ln1g, const float* __restrict__ ln1b,
              const float* __restrict__ f1b,  const float* __restrict__ f2bv,
              const float* __restrict__ ln2g, const float* __restrict__ ln2b,
              const float* __restrict__ o1b,  const float* __restrict__ o2b,
              const unsigned short* __restrict__ wfrag,
              float* __restrict__ out, int nvox)
{
  __shared__ unsigned short smem[2 * 64 * 64];   // 16 KB: 2 waves x 8 KB
  const int tid  = threadIdx.x;
  const int wv   = tid >> 6;
  const int lane = tid & 63;
  unsigned short* X = smem + wv * (64*64);  // rows 0..47: hidden -> tok12 -> K -> V -> ffn-h -> op1-h
  unsigned short* Q = X + 48*64;            // rows 0..15: q -> ctx -> postLN1 -> postLN2

  const int v0 = (blockIdx.x * 2 + wv) * 16;
  if (v0 >= nvox) return;                   // tail waves (no barriers -> safe)
  const int cl = lane & 15;
  const int r0 = (lane >> 4) << 2;

  // ======== Phase A: point aggregation (4 lanes per voxel) ========
  // total valid count == num_points (randint < 48); only CURRENT needs a
  // mask-accumulate; history = total - current.
  const int vi = lane >> 2, pq = lane & 3;
  const int np = num_points[v0 + vi];
  float ts[8] = {0,0,0,0,0,0,0,0}, cs[8] = {0,0,0,0,0,0,0,0};
  float cc = 0.f;
  const float4* vp = (const float4*)(vox + (size_t)(v0 + vi) * 384);
  #pragma unroll
  for (int k = 0; k < 12; ++k){
    int p = pq + (k << 2);
    float4 a = vp[p*2], b = vp[p*2 + 1];
    float pm = (p < np) ? 1.f : 0.f;
    float cm = (b.w > 0.5f) ? pm : 0.f;   // current: flag>0.5 & in-range
    cc += cm;
    ts[0] += a.x*pm; ts[1] += a.y*pm; ts[2] += a.z*pm; ts[3] += a.w*pm;
    ts[4] += b.x*pm; ts[5] += b.y*pm; ts[6] += b.z*pm; ts[7] += b.w*pm;
    cs[0] += a.x*cm; cs[1] += a.y*cm; cs[2] += a.z*cm; cs[3] += a.w*cm;
    cs[4] += b.x*cm; cs[5] += b.y*cm; cs[6] += b.z*cm; cs[7] += b.w*cm;
  }
  // intra-quad butterfly via DPP (pure VALU, no LDS pipe)
  cc = dppadd<0xB1>(cc);
  #pragma unroll
  for (int j = 0; j < 8; ++j){ ts[j] = dppadd<0xB1>(ts[j]); cs[j] = dppadd<0xB1>(cs[j]); }
  cc = dppadd<0x4E>(cc);
  #pragma unroll
  for (int j = 0; j < 8; ++j){ ts[j] = dppadd<0x4E>(ts[j]); cs[j] = dppadd<0x4E>(cs[j]); }

  const float tc  = (float)np;            // exact: all p < np are valid
  const float hc  = tc - cc;
  const float icc = 1.f / fmaxf(cc, 1.f);
  const float ihc = 1.f / fmaxf(hc, 1.f);
  const unsigned int myfw = (cc > 0.f ? 1u : 0u) | (hc > 0.f ? 2u : 0u);

  // Build pp-GEMM1 A-fragments in-register (16 bpermutes; no LDS staging).
  bf16x8 ac, ah;
  {
    const int src = cl * 4;   // any lane of voxel (lane&15) has the full sums
    float cf[8], hf[8];
    #pragma unroll
    for (int i = 0; i < 8; ++i){
      cf[i] = __shfl(cs[i]*icc, src);
      hf[i] = __shfl((ts[i] - cs[i])*ihc, src);
    }
    union { bf16x8 v; unsigned short u[8]; } rc, rh;
    #pragma unroll
    for (int i = 0; i < 8; ++i){
      rc.u[i] = (lane < 16) ? f2bf(cf[i]) : (unsigned short)0;
      rh.u[i] = (lane < 16) ? f2bf(hf[i]) : (unsigned short)0;
    }
    ac = rc.v; ah = rh.v;
  }

  // Weight prefetch batches: WA/WB alternate, loaded one GEMM-phase ahead.
  bf16x8 WA[8], WB[8];
  #pragma unroll
  for (int i = 0; i < 4; ++i) WA[i] = ldB(wfrag, 0 + i, lane);   // B1 (pp_w1)
  ld8(WB, wfrag, 4, lane);                                       // B2 (pp_w2)

  // ======== Phase B1: point_proj 8->64 relu (weights in WA) ========
  #pragma unroll
  for (int nt = 0; nt < 4; ++nt){
    float bb = pp_b1[nt*16 + cl];
    f32x4 c0 = {bb, bb, bb, bb}, c1 = {bb, bb, bb, bb};
    c0 = MF(ac, WA[nt], c0);
    c1 = MF(ah, WA[nt], c1);
    #pragma unroll
    for (int r = 0; r < 4; ++r){ c0[r] = fmaxf(c0[r], 0.f); c1[r] = fmaxf(c1[r], 0.f); }
    stC(X, 0, nt, c0, lane);   // hidden(cur) rows 0..15
    stC(X, 1, nt, c1, lane);   // hidden(his) rows 16..31
  }
  ld8(WA, wfrag, 12, lane);                                      // prefetch Cq

  // ======== Phase B2: point_proj 64->64 (weights in WB) ========
  {
    bf16x8 hfr[2][2];
    #pragma unroll
    for (int m = 0; m < 2; ++m)
      #pragma unroll
      for (int kt = 0; kt < 2; ++kt) hfr[m][kt] = ldA(X, m, kt, lane);
    // reads precede overwriting stores in program order (per-wave LDS order)
    #pragma unroll
    for (int m = 0; m < 2; ++m){
      #pragma unroll
      for (int nt = 0; nt < 4; ++nt){
        float bb = pp_b2[nt*16 + cl];
        f32x4 c = {bb, bb, bb, bb};
        c = MF(hfr[m][0], WB[nt*2 + 0], c);
        c = MF(hfr[m][1], WB[nt*2 + 1], c);
        stC(X, m, nt, c, lane);   // token1 rows 0..15, token2 rows 16..31
      }
    }
  }
  ld8(WB, wfrag, 20, lane);                                      // prefetch CK

  // ======== Phase C: token0 A-frags + token1/2 A-frags ========
  bf16x8 at[3][2];
  {
    const float* s = vf + (size_t)(v0 + cl) * 64 + ((lane >> 4) << 3);
    #pragma unroll
    for (int kt = 0; kt < 2; ++kt){
      float4 x0 = *(const float4*)(s + kt*32);
      float4 x1 = *(const float4*)(s + kt*32 + 4);
      float f[8] = {x0.x, x0.y, x0.z, x0.w, x1.x, x1.y, x1.z, x1.w};
      at[0][kt] = pack8(f);
    }
    #pragma unroll
    for (int kt = 0; kt < 2; ++kt){
      at[1][kt] = ldA(X, 0, kt, lane);
      at[2][kt] = ldA(X, 1, kt, lane);
    }
  }

  // ======== Phase Cq: q projection (weights in WA), scaled 0.25 -> Q ========
  #pragma unroll
  for (int nt = 0; nt < 4; ++nt){
    float bb = ipb[nt*16 + cl];
    f32x4 c = {bb, bb, bb, bb};
    c = MF(at[0][0], WA[nt*2 + 0], c);
    c = MF(at[0][1], WA[nt*2 + 1], c);
    #pragma unroll
    for (int r = 0; r < 4; ++r) c[r] *= 0.25f;
    stC(Q, 0, nt, c, lane);
  }
  ld8(WA, wfrag, 28, lane);                                      // prefetch C2V

  // ======== Phase CK: K projection, 3 tokens (weights in WB) -> X ========
  #pragma unroll
  for (int m = 0; m < 3; ++m){
    #pragma unroll
    for (int nt = 0; nt < 4; ++nt){
      float bb = ipb[64 + nt*16 + cl];
      f32x4 c = {bb, bb, bb, bb};
      c = MF(at[m][0], WB[nt*2 + 0], c);
      c = MF(at[m][1], WB[nt*2 + 1], c);
      stC(X, m, nt, c, lane);
    }
  }
  ld8(WB, wfrag, 36, lane);                                      // prefetch E

  // ======== Phase D1: scores + softmax (lane = (voxel, head)) ========
  const int av = cl, hh2 = lane >> 4;
  float p0, p1, p2;
  {
    unsigned int fw = (unsigned int)__shfl((int)myfw, av*4);
    bool caZ = (fw & 1u) != 0, hpZ = (fw & 2u) != 0;
    float q[16]; ld16(Q, av, hh2*16, q);
    float sc[3];
    #pragma unroll
    for (int m = 0; m < 3; ++m){
      float kv[16]; ld16(X, m*16 + av, hh2*16, kv);
      float d = 0.f;
      #pragma unroll
      for (int j = 0; j < 16; ++j) d += q[j]*kv[j];
      sc[m] = d;
    }
    float mx = sc[0];
    mx = caZ ? fmaxf(mx, sc[1]) : mx;
    mx = hpZ ? fmaxf(mx, sc[2]) : mx;
    p0 = __expf(sc[0] - mx);
    p1 = caZ ? __expf(sc[1] - mx) : 0.f;
    p2 = hpZ ? __expf(sc[2] - mx) : 0.f;
    float inv = 1.f / (p0 + p1 + p2);
    p0 *= inv; p1 *= inv; p2 *= inv;
  }

  // ======== Phase C2V: V projection (weights in WA) -> X ========
  #pragma unroll
  for (int m = 0; m < 3; ++m){
    #pragma unroll
    for (int nt = 0; nt < 4; ++nt){
      float bb = ipb[128 + nt*16 + cl];
      f32x4 c = {bb, bb, bb, bb};
      c = MF(at[m][0], WA[nt*2 + 0], c);
      c = MF(at[m][1], WA[nt*2 + 1], c);
      stC(X, m, nt, c, lane);
    }
  }
  ld8(WA, wfrag, 44, lane);                                      // prefetch F1a

  // ======== Phase D2: ctx = p . V  -> Q (overwrites q) ========
  {
    float ctx[16];
    float vv[16];
    ld16(X, av, hh2*16, vv);
    #pragma unroll
    for (int j = 0; j < 16; ++j) ctx[j] = p0*vv[j];
    ld16(X, 16 + av, hh2*16, vv);
    #pragma unroll
    for (int j = 0; j < 16; ++j) ctx[j] += p1*vv[j];
    ld16(X, 32 + av, hh2*16, vv);
    #pragma unroll
    for (int j = 0; j < 16; ++j) ctx[j] += p2*vv[j];
    st16(Q, av, hh2*16, ctx);
  }

  // ======== Phase E: attn_out + residual + LN1 (weights in WB) ========
  f32x4 res1[4];
  {
    bf16x8 a0 = ldA(Q, 0, 0, lane), a1 = ldA(Q, 0, 1, lane);
    float rv[16];
    #pragma unroll
    for (int nt = 0; nt < 4; ++nt)
      #pragma unroll
      for (int r = 0; r < 4; ++r)
        rv[nt*4 + r] = vf[(size_t)(v0 + r0 + r)*64 + nt*16 + cl];
    #pragma unroll
    for (int nt = 0; nt < 4; ++nt){
      float bb = outb[nt*16 + cl];
      f32x4 c = {bb, bb, bb, bb};
      c = MF(a0, WB[nt*2 + 0], c);
      c = MF(a1, WB[nt*2 + 1], c);
      #pragma unroll
      for (int r = 0; r < 4; ++r) c[r] += rv[nt*4 + r];
      res1[nt] = c;
    }
    layer_norm16(res1, ln1g, ln1b, lane);
    #pragma unroll
    for (int nt = 0; nt < 4; ++nt) stC(Q, 0, nt, res1[nt], lane);
  }
  // prefetch Fw2a (ffn_w2, k-half 0): frags 60+4nt, 61+4nt
  #pragma unroll
  for (int nt = 0; nt < 4; ++nt){
    WB[2*nt + 0] = ldB(wfrag, 60 + 4*nt + 0, lane);
    WB[2*nt + 1] = ldB(wfrag, 60 + 4*nt + 1, lane);
  }

  // ======== Phase F: FFN (64->128 relu ->64) + residual + LN2 ========
  f32x4 tk2[4];
  {
    bf16x8 a0 = ldA(Q, 0, 0, lane), a1 = ldA(Q, 0, 1, lane);
    #pragma unroll
    for (int nt = 0; nt < 4; ++nt){
      float bb = f2bv[nt*16 + cl];
      tk2[nt] = (f32x4){bb, bb, bb, bb};
    }
    // F1a: h cols 0..63 (weights in WA)
    #pragma unroll
    for (int nt = 0; nt < 4; ++nt){
      float bb = f1b[nt*16 + cl];
      f32x4 c = {bb, bb, bb, bb};
      c = MF(a0, WA[nt*2 + 0], c);
      c = MF(a1, WA[nt*2 + 1], c);
      #pragma unroll
      for (int r = 0; r < 4; ++r) c[r] = fmaxf(c[r], 0.f);
      stC(X, 0, nt, c, lane);
    }
    ld8(WA, wfrag, 52, lane);                                    // prefetch F1b
    // Fw2a (weights in WB)
    {
      bf16x8 h0 = ldA(X, 0, 0, lane), h1 = ldA(X, 0, 1, lane);
      #pragma unroll
      for (int nt = 0; nt < 4; ++nt){
        tk2[nt] = MF(h0, WB[nt*2 + 0], tk2[nt]);
        tk2[nt] = MF(h1, WB[nt*2 + 1], tk2[nt]);
      }
    }
    // prefetch Fw2b: frags 62+4nt, 63+4nt
    #pragma unroll
    for (int nt = 0; nt < 4; ++nt){
      WB[2*nt + 0] = ldB(wfrag, 60 + 4*nt + 2, lane);
      WB[2*nt + 1] = ldB(wfrag, 60 + 4*nt + 3, lane);
    }
    // F1b: h cols 64..127 (weights in WA; h reads above precede these stores)
    #pragma unroll
    for (int nt = 0; nt < 4; ++nt){
      float bb = f1b[(nt + 4)*16 + cl];
      f32x4 c = {bb, bb, bb, bb};
      c = MF(a0, WA[nt*2 + 0], c);
      c = MF(a1, WA[nt*2 + 1], c);
      #pragma unroll
      for (int r = 0; r < 4; ++r) c[r] = fmaxf(c[r], 0.f);
      stC(X, 0, nt, c, lane);
    }
    ld8(WA, wfrag, 76, lane);                                    // prefetch G1
    // Fw2b (weights in WB)
    {
      bf16x8 h0 = ldA(X, 0, 0, lane), h1 = ldA(X, 0, 1, lane);
      #pragma unroll
      for (int nt = 0; nt < 4; ++nt){
        tk2[nt] = MF(h0, WB[nt*2 + 0], tk2[nt]);
        tk2[nt] = MF(h1, WB[nt*2 + 1], tk2[nt]);
      }
    }
    ld8(WB, wfrag, 84, lane);                                    // prefetch G2
    #pragma unroll
    for (int nt = 0; nt < 4; ++nt)
      #pragma unroll
      for (int r = 0; r < 4; ++r) tk2[nt][r] += res1[nt][r];
    layer_norm16(tk2, ln2g, ln2b, lane);
    #pragma unroll
    for (int nt = 0; nt < 4; ++nt) stC(Q, 0, nt, tk2[nt], lane);
  }

  // ======== Phase G: output MLP + gate + final residual ========
  {
    bf16x8 a0 = ldA(Q, 0, 0, lane), a1 = ldA(Q, 0, 1, lane);
    // G1 (weights in WA)
    #pragma unroll
    for (int nt = 0; nt < 4; ++nt){
      float bb = o1b[nt*16 + cl];
      f32x4 c = {bb, bb, bb, bb};
      c = MF(a0, WA[nt*2 + 0], c);
      c = MF(a1, WA[nt*2 + 1], c);
      #pragma unroll
      for (int r = 0; r < 4; ++r) c[r] = fmaxf(c[r], 0.f);
      stC(X, 0, nt, c, lane);
    }
    bf16x8 b0 = ldA(X, 0, 0, lane), b1 = ldA(X, 0, 1, lane);
    // hoist the per-row history gates (repeat across nt)
    float keep[4];
    #pragma unroll
    for (int r = 0; r < 4; ++r){
      unsigned int fw2 = (unsigned int)__shfl((int)myfw, (r0 + r)*4);
      keep[r] = (fw2 & 2u) ? 1.f : 0.f;
    }
    // G2 (weights in WB)
    #pragma unroll
    for (int nt = 0; nt < 4; ++nt){
      float bb = o2b[nt*16 + cl];
      f32x4 c = {bb, bb, bb, bb};
      c = MF(b0, WB[nt*2 + 0], c);
      c = MF(b1, WB[nt*2 + 1], c);
      #pragma unroll
      for (int r = 0; r < 4; ++r){
        size_t idx = (size_t)(v0 + r0 + r)*64 + nt*16 + cl;
        out[idx] = vf[idx] + keep[r] * c[r];
      }
    }
  }
}

extern "C" void kernel_launch(void* const* d_in, const int* in_sizes, int n_in,
                              void* d_out, int out_size, void* d_ws, size_t ws_size,
                              hipStream_t stream)
{
  (void)n_in; (void)out_size; (void)ws_size;
  const float* vf    = (const float*)d_in[0];
  const float* vox   = (const float*)d_in[1];
  const float* pp_w1 = (const float*)d_in[2];
  const float* pp_b1 = (const float*)d_in[3];
  const float* pp_w2 = (const float*)d_in[4];
  const float* pp_b2 = (const float*)d_in[5];
  const float* ipw   = (const float*)d_in[6];
  const float* ipb   = (const float*)d_in[7];
  const float* outw  = (const float*)d_in[8];
  const float* outb  = (const float*)d_in[9];
  const float* ln1g  = (const float*)d_in[10];
  const float* ln1b  = (const float*)d_in[11];
  const float* f1w   = (const float*)d_in[12];
  const float* f1b   = (const float*)d_in[13];
  const float* f2w   = (const float*)d_in[14];
  const float* f2b   = (const float*)d_in[15];
  const float* ln2g  = (const float*)d_in[16];
  const float* ln2b  = (const float*)d_in[17];
  const float* o1w   = (const float*)d_in[18];
  const float* o1b   = (const float*)d_in[19];
  const float* o2w   = (const float*)d_in[20];
  const float* o2b   = (const float*)d_in[21];
  const int*   npts  = (const int*)d_in[22];
  unsigned short* wfrag = (unsigned short*)d_ws;   // 92*512*2 = 94208 B
  float* out = (float*)d_out;

  const int nvox = in_sizes[0] / 64;       // 100000
  const int ngrp = nvox / 16;              // 6250 wave-groups
  const int nblk = (ngrp + 1) / 2;         // 3125 blocks x 2 waves
  tva_pack_weights<<<92, 64, 0, stream>>>(pp_w1, pp_w2, ipw, outw, f1w, f2w, o1w, o2w, wfrag);
  tva_main<<<nblk, 128, 0, stream>>>(vf, vox, npts, pp_b1, pp_b2, ipb, outb,
                                     ln1g, ln1b, f1b, f2b, ln2g, ln2b, o1b, o2b,
                                     wfrag, out, nvox);
}

// Round 17
// 68.072 us; speedup vs baseline: 1.1597x; 1.0042x over previous
//
#include <hip/hip_runtime.h>

// TemporalVoxelAttention — MFMA (bf16) fused.
// R17: REVERT to R14 (best passing: 68.36 us). R15/R16's wide-C-write via
// in-quad DPP transpose failed twice with an identical deterministic error
// (absmax 0.6328125) despite thrice-verified butterfly algebra and a
// MFMA->DPP hazard shield — root cause not identifiable at source level;
// lane abandoned per 2-strike rule. R14 = serialized-op-minimized design:
// DPP quad/row reduces (no LDS-pipe bpermutes in aggregation/LN), weight
// prefetch WA/WB one GEMM-phase ahead, 2 waves x 64 thr, 16 KB LDS,
// fence-free (per-wave LDS program order), tc == num_points shortcut.
// d_ws holds weights pre-packed into MFMA B-fragment layout (94208 B).

using bf16x8 = __attribute__((ext_vector_type(8))) __bf16;
using f32x4  = __attribute__((ext_vector_type(4))) float;

#define DEV static __device__ __forceinline__

// DPP add: x + lane-permuted x. Pure VALU, no LDS pipe.
// quad_perm 0xB1 = xor1, 0x4E = xor2; row_ror:4 = 0x124, row_ror:8 = 0x128.
template<int CTRL>
DEV float dppadd(float x){
  union { float f; int i; } a, b;
  a.f = x;
  b.i = __builtin_amdgcn_update_dpp(0, a.i, CTRL, 0xF, 0xF, true);
  return x + b.f;
}

DEV unsigned short f2bf(float f){
  union { float f; unsigned int i; } v; v.f = f;
  return (unsigned short)((v.i + 0x8000u) >> 16);   // round-half-up to bf16
}

// LDS matrices: [rows][64] bf16 (128-B rows), XOR-swizzle byte ^= ((row&7)<<4).
DEV unsigned short* lp(unsigned short* base, int row, int col){
  int byte = (col << 1) ^ ((row & 7) << 4);
  return (unsigned short*)((char*)base + (row << 7) + byte);
}

// A-fragment: lane holds A[row = mt*16 + (lane&15)][k = kt*32 + (lane>>4)*8 + i]
DEV bf16x8 ldA(const unsigned short* base, int mt, int kt, int lane){
  int row = mt*16 + (lane & 15);
  int col = kt*32 + ((lane >> 4) << 3);
  return *(const bf16x8*)lp((unsigned short*)base, row, col);
}
// B-fragment: pre-packed in ws, lane-contiguous 16B
DEV bf16x8 ldB(const unsigned short* w, int frag, int lane){
  return *(const bf16x8*)(w + (size_t)frag*512 + (size_t)lane*8);
}
// Load 8 consecutive frags into a register batch (static indices).
DEV void ld8(bf16x8* W, const unsigned short* w, int base, int lane){
  #pragma unroll
  for (int i = 0; i < 8; ++i) W[i] = ldB(w, base + i, lane);
}
// C/D: col = lane&15, row = mt*16 + (lane>>4)*4 + r
DEV void stC(unsigned short* base, int mt, int nt, f32x4 c, int lane){
  int col  = nt*16 + (lane & 15);
  int row0 = mt*16 + ((lane >> 4) << 2);
  #pragma unroll
  for (int r = 0; r < 4; ++r) *lp(base, row0 + r, col) = f2bf(c[r]);
}
DEV f32x4 MF(bf16x8 a, bf16x8 b, f32x4 c){
  return __builtin_amdgcn_mfma_f32_16x16x32_bf16(a, b, c, 0, 0, 0);
}

DEV void ld16(const unsigned short* base, int row, int col0, float* o){
  uint4 a = *(const uint4*)lp((unsigned short*)base, row, col0);
  uint4 b = *(const uint4*)lp((unsigned short*)base, row, col0 + 8);
  unsigned int w[8] = {a.x, a.y, a.z, a.w, b.x, b.y, b.z, b.w};
  #pragma unroll
  for (int i = 0; i < 8; ++i){
    union { unsigned int u; float f; } lo, hi;
    lo.u = w[i] << 16; hi.u = w[i] & 0xFFFF0000u;
    o[2*i] = lo.f; o[2*i+1] = hi.f;
  }
}
DEV void st16(unsigned short* base, int row, int col0, const float* f){
  unsigned int w[8];
  #pragma unroll
  for (int i = 0; i < 8; ++i)
    w[i] = (unsigned int)f2bf(f[2*i]) | ((unsigned int)f2bf(f[2*i+1]) << 16);
  *(uint4*)lp(base, row, col0)     = make_uint4(w[0], w[1], w[2], w[3]);
  *(uint4*)lp(base, row, col0 + 8) = make_uint4(w[4], w[5], w[6], w[7]);
}

DEV bf16x8 pack8(const float* f){
  union { bf16x8 v; unsigned short u[8]; } r;
  #pragma unroll
  for (int i = 0; i < 8; ++i) r.u[i] = f2bf(f[i]);
  return r.v;
}

// LayerNorm over 64 cols for one 16-row M-tile held as 4 C-frags.
// All-DPP reduction (quad_perm + row_ror), zero LDS-pipe ops.
DEV void layer_norm16(f32x4 x[4], const float* g, const float* b, int lane){
  float s[4], s2[4];
  #pragma unroll
  for (int r = 0; r < 4; ++r){
    s[r]  = x[0][r] + x[1][r] + x[2][r] + x[3][r];
    s2[r] = x[0][r]*x[0][r] + x[1][r]*x[1][r] + x[2][r]*x[2][r] + x[3][r]*x[3][r];
  }
  #pragma unroll
  for (int r = 0; r < 4; ++r){
    s[r]  = dppadd<0xB1>(s[r]);    s2[r] = dppadd<0xB1>(s2[r]);
    s[r]  = dppadd<0x4E>(s[r]);    s2[r] = dppadd<0x4E>(s2[r]);
    s[r]  = dppadd<0x124>(s[r]);   s2[r] = dppadd<0x124>(s2[r]);
    s[r]  = dppadd<0x128>(s[r]);   s2[r] = dppadd<0x128>(s2[r]);
  }
  float mu[4], rs[4];
  #pragma unroll
  for (int r = 0; r < 4; ++r){
    mu[r] = s[r] * (1.f/64.f);
    float var = s2[r] * (1.f/64.f) - mu[r]*mu[r];
    rs[r] = rsqrtf(var + 1e-5f);
  }
  const int cl = lane & 15;
  #pragma unroll
  for (int nt = 0; nt < 4; ++nt){
    float gg = g[nt*16 + cl], bb = b[nt*16 + cl];
    #pragma unroll
    for (int r = 0; r < 4; ++r)
      x[nt][r] = (x[nt][r] - mu[r]) * rs[r] * gg + bb;
  }
}

// ---------------- weight packing (unchanged) ----------------
// 0: pp_w1 (K=8 pad 32, N=64)   base 0,  4 frags
// 1: pp_w2 (K=64,  N=64)        base 4,  8
// 2: in_proj (K=64, N=192)      base 12, 24 (q 12..19, k 20..27, v 28..35)
// 3: out_w (K=64, N=64)         base 36, 8
// 4: ffn_w1 (K=64, N=128)       base 44, 16
// 5: ffn_w2 (K=128, N=64)       base 60, 16
// 6: op_w1 (K=64, N=64)         base 76, 8
// 7: op_w2 (K=64, N=64)         base 84, 8   -> 92 frags total
__global__ void tva_pack_weights(const float* __restrict__ pp_w1, const float* __restrict__ pp_w2,
                                 const float* __restrict__ in_proj_w, const float* __restrict__ out_w,
                                 const float* __restrict__ ffn_w1, const float* __restrict__ ffn_w2,
                                 const float* __restrict__ op_w1, const float* __restrict__ op_w2,
                                 unsigned short* __restrict__ ws)
{
  int b = blockIdx.x, lane = threadIdx.x;
  const float* W; int base, ktiles, K;
  if      (b < 4)  { W = pp_w1;     base = 0;  ktiles = 1; K = 8;   }
  else if (b < 12) { W = pp_w2;     base = 4;  ktiles = 2; K = 64;  }
  else if (b < 36) { W = in_proj_w; base = 12; ktiles = 2; K = 64;  }
  else if (b < 44) { W = out_w;     base = 36; ktiles = 2; K = 64;  }
  else if (b < 60) { W = ffn_w1;    base = 44; ktiles = 2; K = 64;  }
  else if (b < 76) { W = ffn_w2;    base = 60; ktiles = 4; K = 128; }
  else if (b < 84) { W = op_w1;     base = 76; ktiles = 2; K = 64;  }
  else             { W = op_w2;     base = 84; ktiles = 2; K = 64;  }
  int local = b - base;
  int nt = local / ktiles, kt = local % ktiles;
  int n  = nt*16 + (lane & 15);
  int k0 = kt*32 + ((lane >> 4) << 3);
  unsigned short* dst = ws + (size_t)b*512 + (size_t)lane*8;
  #pragma unroll
  for (int i = 0; i < 8; ++i){
    int k = k0 + i;
    float v = (k < K) ? W[(size_t)n*K + k] : 0.0f;
    dst[i] = f2bf(v);
  }
}

// ---------------- main kernel ----------------
__global__ __launch_bounds__(128)
void tva_main(const float* __restrict__ vf, const float* __restrict__ vox,
              const int* __restrict__ num_points,
              const float* __restrict__ pp_b1, const float* __restrict__ pp_b2,
              const float* __restrict__ ipb,  const float* __restrict__ outb,
              const float* __restrict__ ln1g, const float* __restrict__ ln1b,
              const float* __restrict__ f1b,  const float* __restrict__ f2bv,
              const float* __restrict__ ln2g, const float* __restrict__ ln2b,
              const float* __restrict__ o1b,  const float* __restrict__ o2b,
              const unsigned short* __restrict__ wfrag,
              float* __restrict__ out, int nvox)
{
  __shared__ unsigned short smem[2 * 64 * 64];   // 16 KB: 2 waves x 8 KB
  const int tid  = threadIdx.x;
  const int wv   = tid >> 6;
  const int lane = tid & 63;
  unsigned short* X = smem + wv * (64*64);  // rows 0..47: hidden -> tok12 -> K -> V -> ffn-h -> op1-h
  unsigned short* Q = X + 48*64;            // rows 0..15: q -> ctx -> postLN1 -> postLN2

  const int v0 = (blockIdx.x * 2 + wv) * 16;
  if (v0 >= nvox) return;                   // tail waves (no barriers -> safe)
  const int cl = lane & 15;
  const int r0 = (lane >> 4) << 2;

  // ======== Phase A: point aggregation (4 lanes per voxel) ========
  const int vi = lane >> 2, pq = lane & 3;
  const int np = num_points[v0 + vi];
  float ts[8] = {0,0,0,0,0,0,0,0}, cs[8] = {0,0,0,0,0,0,0,0};
  float cc = 0.f;
  const float4* vp = (const float4*)(vox + (size_t)(v0 + vi) * 384);
  #pragma unroll
  for (int k = 0; k < 12; ++k){
    int p = pq + (k << 2);
    float4 a = vp[p*2], b = vp[p*2 + 1];
    float pm = (p < np) ? 1.f : 0.f;
    float cm = (b.w > 0.5f) ? pm : 0.f;   // current: flag>0.5 & in-range
    cc += cm;
    ts[0] += a.x*pm; ts[1] += a.y*pm; ts[2] += a.z*pm; ts[3] += a.w*pm;
    ts[4] += b.x*pm; ts[5] += b.y*pm; ts[6] += b.z*pm; ts[7] += b.w*pm;
    cs[0] += a.x*cm; cs[1] += a.y*cm; cs[2] += a.z*cm; cs[3] += a.w*cm;
    cs[4] += b.x*cm; cs[5] += b.y*cm; cs[6] += b.z*cm; cs[7] += b.w*cm;
  }
  // intra-quad butterfly via DPP (pure VALU, no LDS pipe)
  cc = dppadd<0xB1>(cc);
  #pragma unroll
  for (int j = 0; j < 8; ++j){ ts[j] = dppadd<0xB1>(ts[j]); cs[j] = dppadd<0xB1>(cs[j]); }
  cc = dppadd<0x4E>(cc);
  #pragma unroll
  for (int j = 0; j < 8; ++j){ ts[j] = dppadd<0x4E>(ts[j]); cs[j] = dppadd<0x4E>(cs[j]); }

  const float tc  = (float)np;            // exact: all p < np are valid
  const float hc  = tc - cc;
  const float icc = 1.f / fmaxf(cc, 1.f);
  const float ihc = 1.f / fmaxf(hc, 1.f);
  const unsigned int myfw = (cc > 0.f ? 1u : 0u) | (hc > 0.f ? 2u : 0u);

  // Build pp-GEMM1 A-fragments in-register (16 bpermutes; no LDS staging).
  bf16x8 ac, ah;
  {
    const int src = cl * 4;   // any lane of voxel (lane&15) has the full sums
    float cf[8], hf[8];
    #pragma unroll
    for (int i = 0; i < 8; ++i){
      cf[i] = __shfl(cs[i]*icc, src);
      hf[i] = __shfl((ts[i] - cs[i])*ihc, src);
    }
    union { bf16x8 v; unsigned short u[8]; } rc, rh;
    #pragma unroll
    for (int i = 0; i < 8; ++i){
      rc.u[i] = (lane < 16) ? f2bf(cf[i]) : (unsigned short)0;
      rh.u[i] = (lane < 16) ? f2bf(hf[i]) : (unsigned short)0;
    }
    ac = rc.v; ah = rh.v;
  }

  // Weight prefetch batches: WA/WB alternate, loaded one GEMM-phase ahead.
  bf16x8 WA[8], WB[8];
  #pragma unroll
  for (int i = 0; i < 4; ++i) WA[i] = ldB(wfrag, 0 + i, lane);   // B1 (pp_w1)
  ld8(WB, wfrag, 4, lane);                                       // B2 (pp_w2)

  // ======== Phase B1: point_proj 8->64 relu (weights in WA) ========
  #pragma unroll
  for (int nt = 0; nt < 4; ++nt){
    float bb = pp_b1[nt*16 + cl];
    f32x4 c0 = {bb, bb, bb, bb}, c1 = {bb, bb, bb, bb};
    c0 = MF(ac, WA[nt], c0);
    c1 = MF(ah, WA[nt], c1);
    #pragma unroll
    for (int r = 0; r < 4; ++r){ c0[r] = fmaxf(c0[r], 0.f); c1[r] = fmaxf(c1[r], 0.f); }
    stC(X, 0, nt, c0, lane);   // hidden(cur) rows 0..15
    stC(X, 1, nt, c1, lane);   // hidden(his) rows 16..31
  }
  ld8(WA, wfrag, 12, lane);                                      // prefetch Cq

  // ======== Phase B2: point_proj 64->64 (weights in WB) ========
  {
    bf16x8 hfr[2][2];
    #pragma unroll
    for (int m = 0; m < 2; ++m)
      #pragma unroll
      for (int kt = 0; kt < 2; ++kt) hfr[m][kt] = ldA(X, m, kt, lane);
    // reads precede overwriting stores in program order (per-wave LDS order)
    #pragma unroll
    for (int m = 0; m < 2; ++m){
      #pragma unroll
      for (int nt = 0; nt < 4; ++nt){
        float bb = pp_b2[nt*16 + cl];
        f32x4 c = {bb, bb, bb, bb};
        c = MF(hfr[m][0], WB[nt*2 + 0], c);
        c = MF(hfr[m][1], WB[nt*2 + 1], c);
        stC(X, m, nt, c, lane);   // token1 rows 0..15, token2 rows 16..31
      }
    }
  }
  ld8(WB, wfrag, 20, lane);                                      // prefetch CK

  // ======== Phase C: token0 A-frags + token1/2 A-frags ========
  bf16x8 at[3][2];
  {
    const float* s = vf + (size_t)(v0 + cl) * 64 + ((lane >> 4) << 3);
    #pragma unroll
    for (int kt = 0; kt < 2; ++kt){
      float4 x0 = *(const float4*)(s + kt*32);
      float4 x1 = *(const float4*)(s + kt*32 + 4);
      float f[8] = {x0.x, x0.y, x0.z, x0.w, x1.x, x1.y, x1.z, x1.w};
      at[0][kt] = pack8(f);
    }
    #pragma unroll
    for (int kt = 0; kt < 2; ++kt){
      at[1][kt] = ldA(X, 0, kt, lane);
      at[2][kt] = ldA(X, 1, kt, lane);
    }
  }

  // ======== Phase Cq: q projection (weights in WA), scaled 0.25 -> Q ========
  #pragma unroll
  for (int nt = 0; nt < 4; ++nt){
    float bb = ipb[nt*16 + cl];
    f32x4 c = {bb, bb, bb, bb};
    c = MF(at[0][0], WA[nt*2 + 0], c);
    c = MF(at[0][1], WA[nt*2 + 1], c);
    #pragma unroll
    for (int r = 0; r < 4; ++r) c[r] *= 0.25f;
    stC(Q, 0, nt, c, lane);
  }
  ld8(WA, wfrag, 28, lane);                                      // prefetch C2V

  // ======== Phase CK: K projection, 3 tokens (weights in WB) -> X ========
  #pragma unroll
  for (int m = 0; m < 3; ++m){
    #pragma unroll
    for (int nt = 0; nt < 4; ++nt){
      float bb = ipb[64 + nt*16 + cl];
      f32x4 c = {bb, bb, bb, bb};
      c = MF(at[m][0], WB[nt*2 + 0], c);
      c = MF(at[m][1], WB[nt*2 + 1], c);
      stC(X, m, nt, c, lane);
    }
  }
  ld8(WB, wfrag, 36, lane);                                      // prefetch E

  // ======== Phase D1: scores + softmax (lane = (voxel, head)) ========
  const int av = cl, hh2 = lane >> 4;
  float p0, p1, p2;
  {
    unsigned int fw = (unsigned int)__shfl((int)myfw, av*4);
    bool caZ = (fw & 1u) != 0, hpZ = (fw & 2u) != 0;
    float q[16]; ld16(Q, av, hh2*16, q);
    float sc[3];
    #pragma unroll
    for (int m = 0; m < 3; ++m){
      float kv[16]; ld16(X, m*16 + av, hh2*16, kv);
      float d = 0.f;
      #pragma unroll
      for (int j = 0; j < 16; ++j) d += q[j]*kv[j];
      sc[m] = d;
    }
    float mx = sc[0];
    mx = caZ ? fmaxf(mx, sc[1]) : mx;
    mx = hpZ ? fmaxf(mx, sc[2]) : mx;
    p0 = __expf(sc[0] - mx);
    p1 = caZ ? __expf(sc[1] - mx) : 0.f;
    p2 = hpZ ? __expf(sc[2] - mx) : 0.f;
    float inv = 1.f / (p0 + p1 + p2);
    p0 *= inv; p1 *= inv; p2 *= inv;
  }

  // ======== Phase C2V: V projection (weights in WA) -> X ========
  #pragma unroll
  for (int m = 0; m < 3; ++m){
    #pragma unroll
    for (int nt = 0; nt < 4; ++nt){
      float bb = ipb[128 + nt*16 + cl];
      f32x4 c = {bb, bb, bb, bb};
      c = MF(at[m][0], WA[nt*2 + 0], c);
      c = MF(at[m][1], WA[nt*2 + 1], c);
      stC(X, m, nt, c, lane);
    }
  }
  ld8(WA, wfrag, 44, lane);                                      // prefetch F1a

  // ======== Phase D2: ctx = p . V  -> Q (overwrites q) ========
  {
    float ctx[16];
    float vv[16];
    ld16(X, av, hh2*16, vv);
    #pragma unroll
    for (int j = 0; j < 16; ++j) ctx[j] = p0*vv[j];
    ld16(X, 16 + av, hh2*16, vv);
    #pragma unroll
    for (int j = 0; j < 16; ++j) ctx[j] += p1*vv[j];
    ld16(X, 32 + av, hh2*16, vv);
    #pragma unroll
    for (int j = 0; j < 16; ++j) ctx[j] += p2*vv[j];
    st16(Q, av, hh2*16, ctx);
  }

  // ======== Phase E: attn_out + residual + LN1 (weights in WB) ========
  f32x4 res1[4];
  {
    bf16x8 a0 = ldA(Q, 0, 0, lane), a1 = ldA(Q, 0, 1, lane);
    float rv[16];
    #pragma unroll
    for (int nt = 0; nt < 4; ++nt)
      #pragma unroll
      for (int r = 0; r < 4; ++r)
        rv[nt*4 + r] = vf[(size_t)(v0 + r0 + r)*64 + nt*16 + cl];
    #pragma unroll
    for (int nt = 0; nt < 4; ++nt){
      float bb = outb[nt*16 + cl];
      f32x4 c = {bb, bb, bb, bb};
      c = MF(a0, WB[nt*2 + 0], c);
      c = MF(a1, WB[nt*2 + 1], c);
      #pragma unroll
      for (int r = 0; r < 4; ++r) c[r] += rv[nt*4 + r];
      res1[nt] = c;
    }
    layer_norm16(res1, ln1g, ln1b, lane);
    #pragma unroll
    for (int nt = 0; nt < 4; ++nt) stC(Q, 0, nt, res1[nt], lane);
  }
  // prefetch Fw2a (ffn_w2, k-half 0): frags 60+4nt, 61+4nt
  #pragma unroll
  for (int nt = 0; nt < 4; ++nt){
    WB[2*nt + 0] = ldB(wfrag, 60 + 4*nt + 0, lane);
    WB[2*nt + 1] = ldB(wfrag, 60 + 4*nt + 1, lane);
  }

  // ======== Phase F: FFN (64->128 relu ->64) + residual + LN2 ========
  f32x4 tk2[4];
  {
    bf16x8 a0 = ldA(Q, 0, 0, lane), a1 = ldA(Q, 0, 1, lane);
    #pragma unroll
    for (int nt = 0; nt < 4; ++nt){
      float bb = f2bv[nt*16 + cl];
      tk2[nt] = (f32x4){bb, bb, bb, bb};
    }
    // F1a: h cols 0..63 (weights in WA)
    #pragma unroll
    for (int nt = 0; nt < 4; ++nt){
      float bb = f1b[nt*16 + cl];
      f32x4 c = {bb, bb, bb, bb};
      c = MF(a0, WA[nt*2 + 0], c);
      c = MF(a1, WA[nt*2 + 1], c);
      #pragma unroll
      for (int r = 0; r < 4; ++r) c[r] = fmaxf(c[r], 0.f);
      stC(X, 0, nt, c, lane);
    }
    ld8(WA, wfrag, 52, lane);                                    // prefetch F1b
    // Fw2a (weights in WB)
    {
      bf16x8 h0 = ldA(X, 0, 0, lane), h1 = ldA(X, 0, 1, lane);
      #pragma unroll
      for (int nt = 0; nt < 4; ++nt){
        tk2[nt] = MF(h0, WB[nt*2 + 0], tk2[nt]);
        tk2[nt] = MF(h1, WB[nt*2 + 1], tk2[nt]);
      }
    }
    // prefetch Fw2b: frags 62+4nt, 63+4nt
    #pragma unroll
    for (int nt = 0; nt < 4; ++nt){
      WB[2*nt + 0] = ldB(wfrag, 60 + 4*nt + 2, lane);
      WB[2*nt + 1] = ldB(wfrag, 60 + 4*nt + 3, lane);
    }
    // F1b: h cols 64..127 (weights in WA; h reads above precede these stores)
    #pragma unroll
    for (int nt = 0; nt < 4; ++nt){
      float bb = f1b[(nt + 4)*16 + cl];
      f32x4 c = {bb, bb, bb, bb};
      c = MF(a0, WA[nt*2 + 0], c);
      c = MF(a1, WA[nt*2 + 1], c);
      #pragma unroll
      for (int r = 0; r < 4; ++r) c[r] = fmaxf(c[r], 0.f);
      stC(X, 0, nt, c, lane);
    }
    ld8(WA, wfrag, 76, lane);                                    // prefetch G1
    // Fw2b (weights in WB)
    {
      bf16x8 h0 = ldA(X, 0, 0, lane), h1 = ldA(X, 0, 1, lane);
      #pragma unroll
      for (int nt = 0; nt < 4; ++nt){
        tk2[nt] = MF(h0, WB[nt*2 + 0], tk2[nt]);
        tk2[nt] = MF(h1, WB[nt*2 + 1], tk2[nt]);
      }
    }
    ld8(WB, wfrag, 84, lane);                                    // prefetch G2
    #pragma unroll
    for (int nt = 0; nt < 4; ++nt)
      #pragma unroll
      for (int r = 0; r < 4; ++r) tk2[nt][r] += res1[nt][r];
    layer_norm16(tk2, ln2g, ln2b, lane);
    #pragma unroll
    for (int nt = 0; nt < 4; ++nt) stC(Q, 0, nt, tk2[nt], lane);
  }

  // ======== Phase G: output MLP + gate + final residual ========
  {
    bf16x8 a0 = ldA(Q, 0, 0, lane), a1 = ldA(Q, 0, 1, lane);
    // G1 (weights in WA)
    #pragma unroll
    for (int nt = 0; nt < 4; ++nt){
      float bb = o1b[nt*16 + cl];
      f32x4 c = {bb, bb, bb, bb};
      c = MF(a0, WA[nt*2 + 0], c);
      c = MF(a1, WA[nt*2 + 1], c);
      #pragma unroll
      for (int r = 0; r < 4; ++r) c[r] = fmaxf(c[r], 0.f);
      stC(X, 0, nt, c, lane);
    }
    bf16x8 b0 = ldA(X, 0, 0, lane), b1 = ldA(X, 0, 1, lane);
    // hoist the per-row history gates (repeat across nt)
    float keep[4];
    #pragma unroll
    for (int r = 0; r < 4; ++r){
      unsigned int fw2 = (unsigned int)__shfl((int)myfw, (r0 + r)*4);
      keep[r] = (fw2 & 2u) ? 1.f : 0.f;
    }
    // G2 (weights in WB)
    #pragma unroll
    for (int nt = 0; nt < 4; ++nt){
      float bb = o2b[nt*16 + cl];
      f32x4 c = {bb, bb, bb, bb};
      c = MF(b0, WB[nt*2 + 0], c);
      c = MF(b1, WB[nt*2 + 1], c);
      #pragma unroll
      for (int r = 0; r < 4; ++r){
        size_t idx = (size_t)(v0 + r0 + r)*64 + nt*16 + cl;
        out[idx] = vf[idx] + keep[r] * c[r];
      }
    }
  }
}

extern "C" void kernel_launch(void* const* d_in, const int* in_sizes, int n_in,
                              void* d_out, int out_size, void* d_ws, size_t ws_size,
                              hipStream_t stream)
{
  (void)n_in; (void)out_size; (void)ws_size;
  const float* vf    = (const float*)d_in[0];
  const float* vox   = (const float*)d_in[1];
  const float* pp_w1 = (const float*)d_in[2];
  const float* pp_b1 = (const float*)d_in[3];
  const float* pp_w2 = (const float*)d_in[4];
  const float* pp_b2 = (const float*)d_in[5];
  const float* ipw   = (const float*)d_in[6];
  const float* ipb   = (const float*)d_in[7];
  const float* outw  = (const float*)d_in[8];
  const float* outb  = (const float*)d_in[9];
  const float* ln1g  = (const float*)d_in[10];
  const float* ln1b  = (const float*)d_in[11];
  const float* f1w   = (const float*)d_in[12];
  const float* f1b   = (const float*)d_in[13];
  const float* f2w   = (const float*)d_in[14];
  const float* f2b   = (const float*)d_in[15];
  const float* ln2g  = (const float*)d_in[16];
  const float* ln2b  = (const float*)d_in[17];
  const float* o1w   = (const float*)d_in[18];
  const float* o1b   = (const float*)d_in[19];
  const float* o2w   = (const float*)d_in[20];
  const float* o2b   = (const float*)d_in[21];
  const int*   npts  = (const int*)d_in[22];
  unsigned short* wfrag = (unsigned short*)d_ws;   // 92*512*2 = 94208 B
  float* out = (float*)d_out;

  const int nvox = in_sizes[0] / 64;       // 100000
  const int ngrp = nvox / 16;              // 6250 wave-groups
  const int nblk = (ngrp + 1) / 2;         // 3125 blocks x 2 waves
  tva_pack_weights<<<92, 64, 0, stream>>>(pp_w1, pp_w2, ipw, outw, f1w, f2w, o1w, o2w, wfrag);
  tva_main<<<nblk, 128, 0, stream>>>(vf, vox, npts, pp_b1, pp_b2, ipb, outb,
                                     ln1g, ln1b, f1b, f2b, ln2g, ln2b, o1b, o2b,
                                     wfrag, out, nvox);
}